// Round 1
// baseline (3241.126 us; speedup 1.0000x reference)
//
#include <hip/hip_runtime.h>

constexpr float NEG_SLOPE = 0.2f;
constexpr float SM_EPS = 1e-16f;

__device__ __forceinline__ float lrelu(float x) { return x > 0.f ? x : NEG_SLOPE * x; }

// float atomic max via int encoding: signed-max for >=0, unsigned-min for <0
__device__ __forceinline__ void atomicMaxFloat(float* addr, float v) {
  if (v >= 0.f) atomicMax((int*)addr, __float_as_int(v));
  else          atomicMin((unsigned int*)addr, __float_as_uint(v));
}

__device__ __forceinline__ void load_edge(const void* edges, int i32, int E, int e,
                                          int* s, int* d) {
  if (i32) {
    *s = ((const int*)edges)[e];
    *d = ((const int*)edges)[E + e];
  } else {
    *s = (int)((const long long*)edges)[e];
    *d = (int)((const long long*)edges)[E + e];
  }
}

// Detect whether edge buffer is int32 (flag=1) or int64 (flag=0).
// int32 index pairs read as u64 are >= 2^32 with overwhelming probability.
__global__ void detect_i32_kernel(const unsigned long long* __restrict__ e, int count,
                                  unsigned long long n, int* flag) {
  int t = blockIdx.x * blockDim.x + threadIdx.x;
  if (t < count && e[t] >= n) atomicOr(flag, 1);
}

// XW[row][o] = sum_k X[row][k] * W[o][k]   (x @ W.T), 128x128 W LDS-resident.
__global__ __launch_bounds__(256) void gemm_xw_kernel(
    const float* __restrict__ X, const float* __restrict__ W,
    float* __restrict__ XW, int n) {
  __shared__ float Wt[128 * 128];   // Wt[k][o], transposed W
  __shared__ float xs[64 * 128];    // xs[r][k]
  const int tid = threadIdx.x;
  const int row0 = blockIdx.x * 64;

#pragma unroll
  for (int i = 0; i < 16; ++i) {
    int f = tid + i * 256;                 // [0,4096) float4s of W
    int o = f >> 5;
    int k4 = (f & 31) << 2;
    float4 w = reinterpret_cast<const float4*>(W)[f];
    Wt[(k4 + 0) * 128 + o] = w.x;
    Wt[(k4 + 1) * 128 + o] = w.y;
    Wt[(k4 + 2) * 128 + o] = w.z;
    Wt[(k4 + 3) * 128 + o] = w.w;
  }
#pragma unroll
  for (int i = 0; i < 8; ++i) {
    int f = tid + i * 256;                 // [0,2048) float4s of x tile
    int r = f >> 5;
    int c4 = f & 31;
    int row = row0 + r;
    float4 v = make_float4(0.f, 0.f, 0.f, 0.f);
    if (row < n) v = reinterpret_cast<const float4*>(X)[(size_t)row * 32 + c4];
    reinterpret_cast<float4*>(xs)[f] = v;
  }
  __syncthreads();

  const int tc = tid & 31;   // col group: cols tc*4..+4
  const int tr = tid >> 5;   // row group: rows tr*8..+8
  float acc[8][4];
#pragma unroll
  for (int i = 0; i < 8; ++i)
#pragma unroll
    for (int j = 0; j < 4; ++j) acc[i][j] = 0.f;

  for (int k = 0; k < 128; k += 4) {
    float b[4][4];
#pragma unroll
    for (int kk = 0; kk < 4; ++kk)
      *reinterpret_cast<float4*>(b[kk]) =
          *reinterpret_cast<const float4*>(&Wt[(k + kk) * 128 + tc * 4]);
#pragma unroll
    for (int i = 0; i < 8; ++i) {
      float4 a = *reinterpret_cast<const float4*>(&xs[(tr * 8 + i) * 128 + k]);
#pragma unroll
      for (int j = 0; j < 4; ++j)
        acc[i][j] += a.x * b[0][j] + a.y * b[1][j] + a.z * b[2][j] + a.w * b[3][j];
    }
  }

#pragma unroll
  for (int i = 0; i < 8; ++i) {
    int row = row0 + tr * 8 + i;
    if (row < n) {
      float4 o4 = make_float4(acc[i][0], acc[i][1], acc[i][2], acc[i][3]);
      reinterpret_cast<float4*>(XW)[(size_t)row * 32 + tc] = o4;
    }
  }
}

// a_src/a_dst per (node, head); seed running max with self-loop a_src.
// 4 threads per node, each covers 32 contiguous cols (half a head).
__global__ void attn_node_kernel(const float* __restrict__ XW,
                                 const float* __restrict__ att_s,
                                 const float* __restrict__ att_d,
                                 float* __restrict__ a_src, float* __restrict__ a_dst,
                                 float* __restrict__ mmax, int n) {
  int tid = blockIdx.x * blockDim.x + threadIdx.x;
  int node = tid >> 2;
  int q = tid & 3;
  if (node >= n) return;
  int h = q >> 1;
  const float4* xwv = reinterpret_cast<const float4*>(XW + (size_t)node * 128 + q * 32);
  const float4* asv = reinterpret_cast<const float4*>(att_s + q * 32);
  const float4* adv = reinterpret_cast<const float4*>(att_d + q * 32);
  float ss = 0.f, sd = 0.f;
#pragma unroll
  for (int i = 0; i < 8; ++i) {
    float4 v = xwv[i]; float4 a = asv[i]; float4 d = adv[i];
    ss += v.x * a.x + v.y * a.y + v.z * a.z + v.w * a.w;
    sd += v.x * d.x + v.y * d.y + v.z * d.z + v.w * d.w;
  }
  ss += __shfl_xor(ss, 1);
  sd += __shfl_xor(sd, 1);
  if ((q & 1) == 0) {
    a_src[node * 2 + h] = ss;
    a_dst[node * 2 + h] = sd;
    mmax[node * 2 + h] = ss;   // self-loop seed for max over incoming a_src
  }
}

// mmax[d,h] = max over incoming edges of a_src[s,h]
__global__ void edge_max_kernel(const void* __restrict__ edges, const int* __restrict__ isI32,
                                int E, const float* __restrict__ a_src,
                                float* __restrict__ mmax) {
  int e = blockIdx.x * blockDim.x + threadIdx.x;
  if (e >= E) return;
  int i32 = *isI32;
  int s, d;
  load_edge(edges, i32, E, e, &s, &d);
#pragma unroll
  for (int h = 0; h < 2; ++h) atomicMaxFloat(&mmax[d * 2 + h], a_src[s * 2 + h]);
}

// amax = lrelu(a_dst + m) (in place over mmax); denom seeded with self-loop exp
__global__ void node_seed_kernel(const float* __restrict__ a_src, const float* __restrict__ a_dst,
                                 float* __restrict__ mmax, float* __restrict__ denom, int n2) {
  int t = blockIdx.x * blockDim.x + threadIdx.x;
  if (t >= n2) return;
  float m = mmax[t], ad = a_dst[t], as = a_src[t];
  float am = lrelu(ad + m);
  float ex = expf(lrelu(as + ad) - am);
  mmax[t] = am;
  denom[t] = ex;
}

__global__ void edge_sum_kernel(const void* __restrict__ edges, const int* __restrict__ isI32,
                                int E, const float* __restrict__ a_src,
                                const float* __restrict__ a_dst, const float* __restrict__ amax,
                                float* __restrict__ denom) {
  int e = blockIdx.x * blockDim.x + threadIdx.x;
  if (e >= E) return;
  int i32 = *isI32;
  int s, d;
  load_edge(edges, i32, E, e, &s, &d);
#pragma unroll
  for (int h = 0; h < 2; ++h) {
    float alpha = lrelu(a_src[s * 2 + h] + a_dst[d * 2 + h]);
    atomicAdd(&denom[d * 2 + h], expf(alpha - amax[d * 2 + h]));
  }
}

// rden = 1/(denom+eps) (in place); out = bias + self_coef * xw[node]
__global__ void node_init_kernel(const float* __restrict__ XW, const float* __restrict__ a_src,
                                 const float* __restrict__ a_dst, const float* __restrict__ amax,
                                 float* __restrict__ denom, const float* __restrict__ bias,
                                 float* __restrict__ out, int n) {
  int tid = blockIdx.x * blockDim.x + threadIdx.x;
  int node = tid >> 2;
  int q = tid & 3;
  if (node >= n) return;
  int h = q >> 1;
  float as = a_src[node * 2 + h], ad = a_dst[node * 2 + h];
  float am = amax[node * 2 + h], dn = denom[node * 2 + h];
  float r = 1.f / (dn + SM_EPS);
  float selfc = expf(lrelu(as + ad) - am) * r;
  if ((q & 1) == 0) denom[node * 2 + h] = r;  // wave-lockstep: loads precede store
  const float4* xwv = reinterpret_cast<const float4*>(XW + (size_t)node * 128 + q * 32);
  const float4* bv = reinterpret_cast<const float4*>(bias + q * 32);
  float4* ov = reinterpret_cast<float4*>(out + (size_t)node * 128 + q * 32);
#pragma unroll
  for (int i = 0; i < 8; ++i) {
    float4 v = xwv[i]; float4 b = bv[i];
    ov[i] = make_float4(b.x + selfc * v.x, b.y + selfc * v.y,
                        b.z + selfc * v.z, b.w + selfc * v.w);
  }
}

// Heavy pass: out[d] += coef * xw[s] over all real edges. 32 threads/edge.
__global__ __launch_bounds__(256) void edge_scatter_kernel(
    const void* __restrict__ edges, const int* __restrict__ isI32, int E,
    const float* __restrict__ XW, const float* __restrict__ a_src,
    const float* __restrict__ a_dst, const float* __restrict__ amax,
    const float* __restrict__ rden, float* __restrict__ out) {
  long long gid = (long long)blockIdx.x * blockDim.x + threadIdx.x;
  int e = (int)(gid >> 5);
  int j = (int)(gid & 31);         // float4 slot: cols j*4..+4
  if (e >= E) return;
  int i32 = *isI32;
  int s, d;
  load_edge(edges, i32, E, e, &s, &d);
  int h = j >> 4;
  float alpha = lrelu(a_src[s * 2 + h] + a_dst[d * 2 + h]);
  float coef = expf(alpha - amax[d * 2 + h]) * rden[d * 2 + h];
  float4 v = reinterpret_cast<const float4*>(XW)[(size_t)s * 32 + j];
  float* o = out + (size_t)d * 128 + j * 4;
  atomicAdd(o + 0, coef * v.x);
  atomicAdd(o + 1, coef * v.y);
  atomicAdd(o + 2, coef * v.z);
  atomicAdd(o + 3, coef * v.w);
}

__global__ void elu_kernel(float* __restrict__ buf, int count4) {
  int t = blockIdx.x * blockDim.x + threadIdx.x;
  if (t >= count4) return;
  float4 v = reinterpret_cast<float4*>(buf)[t];
  v.x = v.x > 0.f ? v.x : expm1f(v.x);
  v.y = v.y > 0.f ? v.y : expm1f(v.y);
  v.z = v.z > 0.f ? v.z : expm1f(v.z);
  v.w = v.w > 0.f ? v.w : expm1f(v.w);
  reinterpret_cast<float4*>(buf)[t] = v;
}

extern "C" void kernel_launch(void* const* d_in, const int* in_sizes, int n_in,
                              void* d_out, int out_size, void* d_ws, size_t ws_size,
                              hipStream_t stream) {
  const float* x   = (const float*)d_in[0];
  const void* edges = d_in[1];
  const float* W0  = (const float*)d_in[2];
  const float* as0 = (const float*)d_in[3];
  const float* ad0 = (const float*)d_in[4];
  const float* b0  = (const float*)d_in[5];
  const float* W1  = (const float*)d_in[6];
  const float* as1 = (const float*)d_in[7];
  const float* ad1 = (const float*)d_in[8];
  const float* b1  = (const float*)d_in[9];
  float* out = (float*)d_out;

  const int n = in_sizes[0] / 128;
  const int E = in_sizes[1] / 2;

  float* xw    = (float*)d_ws;
  float* hbuf  = xw + (size_t)n * 128;
  float* a_src = hbuf + (size_t)n * 128;
  float* a_dst = a_src + 2 * (size_t)n;
  float* amax  = a_dst + 2 * (size_t)n;
  float* denom = amax + 2 * (size_t)n;
  int* flag    = (int*)(denom + 2 * (size_t)n);

  hipMemsetAsync(flag, 0, sizeof(int), stream);
  int dcount = E < 4096 ? E : 4096;
  detect_i32_kernel<<<(dcount + 255) / 256, 256, 0, stream>>>(
      (const unsigned long long*)edges, dcount, (unsigned long long)n, flag);

  const float* in_feat = x;
  for (int layer = 0; layer < 2; ++layer) {
    const float* W   = layer ? W1 : W0;
    const float* as_ = layer ? as1 : as0;
    const float* ad_ = layer ? ad1 : ad0;
    const float* bs  = layer ? b1 : b0;
    float* acc = layer ? out : hbuf;

    gemm_xw_kernel<<<(n + 63) / 64, 256, 0, stream>>>(in_feat, W, xw, n);
    attn_node_kernel<<<(n * 4 + 255) / 256, 256, 0, stream>>>(xw, as_, ad_, a_src, a_dst, amax, n);
    edge_max_kernel<<<(E + 255) / 256, 256, 0, stream>>>(edges, flag, E, a_src, amax);
    node_seed_kernel<<<(2 * n + 255) / 256, 256, 0, stream>>>(a_src, a_dst, amax, denom, 2 * n);
    edge_sum_kernel<<<(E + 255) / 256, 256, 0, stream>>>(edges, flag, E, a_src, a_dst, amax, denom);
    node_init_kernel<<<(n * 4 + 255) / 256, 256, 0, stream>>>(xw, a_src, a_dst, amax, denom, bs, acc, n);
    long long sthreads = (long long)E * 32;
    edge_scatter_kernel<<<(unsigned)((sthreads + 255) / 256), 256, 0, stream>>>(
        edges, flag, E, xw, a_src, a_dst, amax, denom, acc);
    elu_kernel<<<(n * 32 + 255) / 256, 256, 0, stream>>>(acc, n * 32);

    in_feat = hbuf;
  }
}

// Round 2
// 526.992 us; speedup vs baseline: 6.1502x; 6.1502x over previous
//
#include <hip/hip_runtime.h>

constexpr float NEG_SLOPE = 0.2f;
constexpr float SM_EPS = 1e-16f;
#define NEG_BIG (-3.0e38f)

__device__ __forceinline__ float lrelu(float x) { return x > 0.f ? x : NEG_SLOPE * x; }

__device__ __forceinline__ void load_edge(const void* edges, int i32, int E, int e,
                                          int* s, int* d) {
  if (i32) {
    *s = ((const int*)edges)[e];
    *d = ((const int*)edges)[E + e];
  } else {
    *s = (int)((const long long*)edges)[e];
    *d = (int)((const long long*)edges)[E + e];
  }
}

// Detect whether edge buffer is int32 (flag=1) or int64 (flag=0).
__global__ void detect_i32_kernel(const unsigned long long* __restrict__ e, int count,
                                  unsigned long long n, int* flag) {
  int t = blockIdx.x * blockDim.x + threadIdx.x;
  if (t < count && e[t] >= n) atomicOr(flag, 1);
}

// XW[row][o] = sum_k X[row][k] * W[o][k]   (x @ W.T), 128x128 W LDS-resident.
__global__ __launch_bounds__(256) void gemm_xw_kernel(
    const float* __restrict__ X, const float* __restrict__ W,
    float* __restrict__ XW, int n) {
  __shared__ float Wt[128 * 128];   // Wt[k][o], transposed W
  __shared__ float xs[64 * 128];    // xs[r][k]
  const int tid = threadIdx.x;
  const int row0 = blockIdx.x * 64;

#pragma unroll
  for (int i = 0; i < 16; ++i) {
    int f = tid + i * 256;                 // [0,4096) float4s of W
    int o = f >> 5;
    int k4 = (f & 31) << 2;
    float4 w = reinterpret_cast<const float4*>(W)[f];
    Wt[(k4 + 0) * 128 + o] = w.x;
    Wt[(k4 + 1) * 128 + o] = w.y;
    Wt[(k4 + 2) * 128 + o] = w.z;
    Wt[(k4 + 3) * 128 + o] = w.w;
  }
#pragma unroll
  for (int i = 0; i < 8; ++i) {
    int f = tid + i * 256;                 // [0,2048) float4s of x tile
    int r = f >> 5;
    int c4 = f & 31;
    int row = row0 + r;
    float4 v = make_float4(0.f, 0.f, 0.f, 0.f);
    if (row < n) v = reinterpret_cast<const float4*>(X)[(size_t)row * 32 + c4];
    reinterpret_cast<float4*>(xs)[f] = v;
  }
  __syncthreads();

  const int tc = tid & 31;
  const int tr = tid >> 5;
  float acc[8][4];
#pragma unroll
  for (int i = 0; i < 8; ++i)
#pragma unroll
    for (int j = 0; j < 4; ++j) acc[i][j] = 0.f;

  for (int k = 0; k < 128; k += 4) {
    float b[4][4];
#pragma unroll
    for (int kk = 0; kk < 4; ++kk)
      *reinterpret_cast<float4*>(b[kk]) =
          *reinterpret_cast<const float4*>(&Wt[(k + kk) * 128 + tc * 4]);
#pragma unroll
    for (int i = 0; i < 8; ++i) {
      float4 a = *reinterpret_cast<const float4*>(&xs[(tr * 8 + i) * 128 + k]);
#pragma unroll
      for (int j = 0; j < 4; ++j)
        acc[i][j] += a.x * b[0][j] + a.y * b[1][j] + a.z * b[2][j] + a.w * b[3][j];
    }
  }

#pragma unroll
  for (int i = 0; i < 8; ++i) {
    int row = row0 + tr * 8 + i;
    if (row < n) {
      float4 o4 = make_float4(acc[i][0], acc[i][1], acc[i][2], acc[i][3]);
      reinterpret_cast<float4*>(XW)[(size_t)row * 32 + tc] = o4;
    }
  }
}

// a_src/a_dst per (node, head). 4 threads per node, 32 cols each.
__global__ void attn_node_kernel(const float* __restrict__ XW,
                                 const float* __restrict__ att_s,
                                 const float* __restrict__ att_d,
                                 float* __restrict__ a_src, float* __restrict__ a_dst,
                                 int n) {
  int tid = blockIdx.x * blockDim.x + threadIdx.x;
  int node = tid >> 2;
  int q = tid & 3;
  if (node >= n) return;
  int h = q >> 1;
  const float4* xwv = reinterpret_cast<const float4*>(XW + (size_t)node * 128 + q * 32);
  const float4* asv = reinterpret_cast<const float4*>(att_s + q * 32);
  const float4* adv = reinterpret_cast<const float4*>(att_d + q * 32);
  float ss = 0.f, sd = 0.f;
#pragma unroll
  for (int i = 0; i < 8; ++i) {
    float4 v = xwv[i]; float4 a = asv[i]; float4 d = adv[i];
    ss += v.x * a.x + v.y * a.y + v.z * a.z + v.w * a.w;
    sd += v.x * d.x + v.y * d.y + v.z * d.z + v.w * d.w;
  }
  ss += __shfl_xor(ss, 1);
  sd += __shfl_xor(sd, 1);
  if ((q & 1) == 0) {
    a_src[node * 2 + h] = ss;
    a_dst[node * 2 + h] = sd;
  }
}

// --- CSR build (once; edges identical for both layers) ---
__global__ void hist_kernel(const void* __restrict__ edges, const int* __restrict__ isI32,
                            int E, int* __restrict__ deg) {
  int e = blockIdx.x * blockDim.x + threadIdx.x;
  if (e >= E) return;
  int i32 = *isI32;
  int s, d;
  load_edge(edges, i32, E, e, &s, &d);
  atomicAdd(&deg[d], 1);
}

// Exclusive scan of deg -> offs[0..n]; deg buffer becomes cursor copy (in place).
__global__ __launch_bounds__(1024) void scan_kernel(int* __restrict__ deg_cursor,
                                                    int* __restrict__ offs, int n) {
  __shared__ int tsum[1024];
  const int tid = threadIdx.x;
  const int chunk = (n + 1023) / 1024;
  const int start = tid * chunk;
  const int end = min(start + chunk, n);
  int s = 0;
  for (int i = start; i < end; ++i) s += deg_cursor[i];
  tsum[tid] = s;
  __syncthreads();
  for (int d = 1; d < 1024; d <<= 1) {
    int v = 0;
    if (tid >= d) v = tsum[tid - d];
    __syncthreads();
    if (tid >= d) tsum[tid] += v;
    __syncthreads();
  }
  int run = (tid == 0) ? 0 : tsum[tid - 1];
  for (int i = start; i < end; ++i) {
    int d_ = deg_cursor[i];
    offs[i] = run;
    deg_cursor[i] = run;   // cursor seed
    run += d_;
  }
  if (tid == 1023) offs[n] = run;
}

__global__ void scatter_kernel(const void* __restrict__ edges, const int* __restrict__ isI32,
                               int E, int* __restrict__ cursor, int* __restrict__ csr) {
  int e = blockIdx.x * blockDim.x + threadIdx.x;
  if (e >= E) return;
  int i32 = *isI32;
  int s, d;
  load_edge(edges, i32, E, e, &s, &d);
  int pos = atomicAdd(&cursor[d], 1);
  csr[pos] = s;
}

// --- Fused per-node GAT: softmax over in-neighbors + weighted gather + bias + ELU.
// One 64-lane wave per node; lane owns output cols [2*lane, 2*lane+1].
__global__ __launch_bounds__(256) void gat_node_kernel(
    const float* __restrict__ XW, const float* __restrict__ a_src,
    const float* __restrict__ a_dst, const int* __restrict__ offs,
    const int* __restrict__ csr, const float* __restrict__ bias,
    float* __restrict__ out, int n) {
  const int node = (int)((blockIdx.x * (unsigned)blockDim.x + threadIdx.x) >> 6);
  const int lane = threadIdx.x & 63;
  if (node >= n) return;
  const int off = offs[node];
  const int deg = offs[node + 1] - off;
  const float2 aself = reinterpret_cast<const float2*>(a_src)[node];
  const float2 ad = reinterpret_cast<const float2*>(a_dst)[node];

  // Phase A: running max of a_src over in-neighbors (seed = self-loop).
  // lrelu is monotone, so amax = lrelu(a_dst + max a_src).
  float m0 = aself.x, m1 = aself.y;
  int s_c = 0;
  float v0_c = NEG_BIG, v1_c = NEG_BIG;
  for (int base = 0; base < deg; base += 64) {
    int i = base + lane;
    int s = 0;
    float v0 = NEG_BIG, v1 = NEG_BIG;
    if (i < deg) {
      s = csr[off + i];
      float2 a = reinterpret_cast<const float2*>(a_src)[s];
      v0 = a.x; v1 = a.y;
    }
    if (base == 0) { s_c = s; v0_c = v0; v1_c = v1; }
    m0 = fmaxf(m0, v0);
    m1 = fmaxf(m1, v1);
  }
#pragma unroll
  for (int d = 32; d; d >>= 1) {
    m0 = fmaxf(m0, __shfl_xor(m0, d));
    m1 = fmaxf(m1, __shfl_xor(m1, d));
  }
  const float am0 = lrelu(ad.x + m0), am1 = lrelu(ad.y + m1);

  // Phase B: softmax denominator.
  float sum0 = 0.f, sum1 = 0.f;
  for (int base = 0; base < deg; base += 64) {
    int i = base + lane;
    float v0 = v0_c, v1 = v1_c;
    if (base != 0) {
      if (i < deg) {
        float2 a = reinterpret_cast<const float2*>(a_src)[csr[off + i]];
        v0 = a.x; v1 = a.y;
      } else { v0 = NEG_BIG; v1 = NEG_BIG; }
    }
    if (i < deg) {
      sum0 += expf(lrelu(v0 + ad.x) - am0);
      sum1 += expf(lrelu(v1 + ad.y) - am1);
    }
  }
#pragma unroll
  for (int d = 32; d; d >>= 1) {
    sum0 += __shfl_xor(sum0, d);
    sum1 += __shfl_xor(sum1, d);
  }
  const float es0 = expf(lrelu(aself.x + ad.x) - am0);
  const float es1 = expf(lrelu(aself.y + ad.y) - am1);
  sum0 += es0; sum1 += es1;
  const float r0 = 1.f / (sum0 + SM_EPS);
  const float r1 = 1.f / (sum1 + SM_EPS);

  // Phase C: out[node] = bias + coef_self*xw[node] + sum coef_e*xw[src_e]
  const float selfc = (lane < 32) ? es0 * r0 : es1 * r1;
  const float2 xself = reinterpret_cast<const float2*>(XW)[(size_t)node * 64 + lane];
  const float2 b = reinterpret_cast<const float2*>(bias)[lane];
  float accx = b.x + selfc * xself.x;
  float accy = b.y + selfc * xself.y;

  for (int base = 0; base < deg; base += 64) {
    int i = base + lane;
    int s = s_c;
    float c0, c1;
    if (base == 0) {
      c0 = expf(lrelu(v0_c + ad.x) - am0) * r0;
      c1 = expf(lrelu(v1_c + ad.y) - am1) * r1;
    } else if (i < deg) {
      s = csr[off + i];
      float2 a = reinterpret_cast<const float2*>(a_src)[s];
      c0 = expf(lrelu(a.x + ad.x) - am0) * r0;
      c1 = expf(lrelu(a.y + ad.y) - am1) * r1;
    } else { s = 0; c0 = 0.f; c1 = 0.f; }
    const int cnt = min(64, deg - base);
    for (int j = 0; j < cnt; ++j) {
      int sj = __shfl(s, j);
      float cf0 = __shfl(c0, j);
      float cf1 = __shfl(c1, j);
      float cf = (lane < 32) ? cf0 : cf1;
      float2 v = reinterpret_cast<const float2*>(XW)[(size_t)sj * 64 + lane];
      accx += cf * v.x;
      accy += cf * v.y;
    }
  }

  // ELU (applied after both layers) + store
  accx = accx > 0.f ? accx : expm1f(accx);
  accy = accy > 0.f ? accy : expm1f(accy);
  reinterpret_cast<float2*>(out)[(size_t)node * 64 + lane] = make_float2(accx, accy);
}

extern "C" void kernel_launch(void* const* d_in, const int* in_sizes, int n_in,
                              void* d_out, int out_size, void* d_ws, size_t ws_size,
                              hipStream_t stream) {
  const float* x    = (const float*)d_in[0];
  const void* edges = d_in[1];
  const float* W0  = (const float*)d_in[2];
  const float* as0 = (const float*)d_in[3];
  const float* ad0 = (const float*)d_in[4];
  const float* b0  = (const float*)d_in[5];
  const float* W1  = (const float*)d_in[6];
  const float* as1 = (const float*)d_in[7];
  const float* ad1 = (const float*)d_in[8];
  const float* b1  = (const float*)d_in[9];
  float* out = (float*)d_out;

  const int n = in_sizes[0] / 128;
  const int E = in_sizes[1] / 2;

  float* xw    = (float*)d_ws;
  float* hbuf  = xw + (size_t)n * 128;
  float* a_src = hbuf + (size_t)n * 128;
  float* a_dst = a_src + 2 * (size_t)n;
  int* offs    = (int*)(a_dst + 2 * (size_t)n);  // n+1
  int* degcur  = offs + (n + 1);                 // n (deg, then cursor)
  int* csr     = degcur + n;                     // E
  int* flag    = csr + E;

  hipMemsetAsync(flag, 0, sizeof(int), stream);
  hipMemsetAsync(degcur, 0, (size_t)n * sizeof(int), stream);

  int dcount = E < 4096 ? E : 4096;
  detect_i32_kernel<<<(dcount + 255) / 256, 256, 0, stream>>>(
      (const unsigned long long*)edges, dcount, (unsigned long long)n, flag);

  // CSR build (edges shared by both layers)
  hist_kernel<<<(E + 255) / 256, 256, 0, stream>>>(edges, flag, E, degcur);
  scan_kernel<<<1, 1024, 0, stream>>>(degcur, offs, n);
  scatter_kernel<<<(E + 255) / 256, 256, 0, stream>>>(edges, flag, E, degcur, csr);

  const float* in_feat = x;
  for (int layer = 0; layer < 2; ++layer) {
    const float* W   = layer ? W1 : W0;
    const float* as_ = layer ? as1 : as0;
    const float* ad_ = layer ? ad1 : ad0;
    const float* bs  = layer ? b1 : b0;
    float* acc = layer ? out : hbuf;

    gemm_xw_kernel<<<(n + 63) / 64, 256, 0, stream>>>(in_feat, W, xw, n);
    attn_node_kernel<<<(n * 4 + 255) / 256, 256, 0, stream>>>(xw, as_, ad_, a_src, a_dst, n);
    gat_node_kernel<<<(n + 3) / 4, 256, 0, stream>>>(xw, a_src, a_dst, offs, csr, bs, acc, n);

    in_feat = hbuf;
  }
}

// Round 3
// 429.382 us; speedup vs baseline: 7.5484x; 1.2273x over previous
//
#include <hip/hip_runtime.h>

constexpr float NEG_SLOPE = 0.2f;
constexpr float SM_EPS = 1e-16f;
#define NEG_BIG (-3.0e38f)

__device__ __forceinline__ float lrelu(float x) { return x > 0.f ? x : NEG_SLOPE * x; }

__device__ __forceinline__ void load_edge(const void* edges, int i32, int E, int e,
                                          int* s, int* d) {
  if (i32) {
    *s = ((const int*)edges)[e];
    *d = ((const int*)edges)[E + e];
  } else {
    *s = (int)((const long long*)edges)[e];
    *d = (int)((const long long*)edges)[E + e];
  }
}

// Detect whether edge buffer is int32 (flag=1) or int64 (flag=0).
__global__ void detect_i32_kernel(const unsigned long long* __restrict__ e, int count,
                                  unsigned long long n, int* flag) {
  int t = blockIdx.x * blockDim.x + threadIdx.x;
  if (t < count && e[t] >= n) atomicOr(flag, 1);
}

// XW[row][o] = sum_k X[row][k] * W[o][k]   (x @ W.T), 128x128 W LDS-resident.
__global__ __launch_bounds__(256) void gemm_xw_kernel(
    const float* __restrict__ X, const float* __restrict__ W,
    float* __restrict__ XW, int n) {
  __shared__ float Wt[128 * 128];   // Wt[k][o], transposed W
  __shared__ float xs[64 * 128];    // xs[r][k]
  const int tid = threadIdx.x;
  const int row0 = blockIdx.x * 64;

#pragma unroll
  for (int i = 0; i < 16; ++i) {
    int f = tid + i * 256;                 // [0,4096) float4s of W
    int o = f >> 5;
    int k4 = (f & 31) << 2;
    float4 w = reinterpret_cast<const float4*>(W)[f];
    Wt[(k4 + 0) * 128 + o] = w.x;
    Wt[(k4 + 1) * 128 + o] = w.y;
    Wt[(k4 + 2) * 128 + o] = w.z;
    Wt[(k4 + 3) * 128 + o] = w.w;
  }
#pragma unroll
  for (int i = 0; i < 8; ++i) {
    int f = tid + i * 256;                 // [0,2048) float4s of x tile
    int r = f >> 5;
    int c4 = f & 31;
    int row = row0 + r;
    float4 v = make_float4(0.f, 0.f, 0.f, 0.f);
    if (row < n) v = reinterpret_cast<const float4*>(X)[(size_t)row * 32 + c4];
    reinterpret_cast<float4*>(xs)[f] = v;
  }
  __syncthreads();

  const int tc = tid & 31;
  const int tr = tid >> 5;
  float acc[8][4];
#pragma unroll
  for (int i = 0; i < 8; ++i)
#pragma unroll
    for (int j = 0; j < 4; ++j) acc[i][j] = 0.f;

  for (int k = 0; k < 128; k += 4) {
    float b[4][4];
#pragma unroll
    for (int kk = 0; kk < 4; ++kk)
      *reinterpret_cast<float4*>(b[kk]) =
          *reinterpret_cast<const float4*>(&Wt[(k + kk) * 128 + tc * 4]);
#pragma unroll
    for (int i = 0; i < 8; ++i) {
      float4 a = *reinterpret_cast<const float4*>(&xs[(tr * 8 + i) * 128 + k]);
#pragma unroll
      for (int j = 0; j < 4; ++j)
        acc[i][j] += a.x * b[0][j] + a.y * b[1][j] + a.z * b[2][j] + a.w * b[3][j];
    }
  }

#pragma unroll
  for (int i = 0; i < 8; ++i) {
    int row = row0 + tr * 8 + i;
    if (row < n) {
      float4 o4 = make_float4(acc[i][0], acc[i][1], acc[i][2], acc[i][3]);
      reinterpret_cast<float4*>(XW)[(size_t)row * 32 + tc] = o4;
    }
  }
}

// a_src/a_dst per (node, head). 4 threads per node, 32 cols each.
__global__ void attn_node_kernel(const float* __restrict__ XW,
                                 const float* __restrict__ att_s,
                                 const float* __restrict__ att_d,
                                 float* __restrict__ a_src, float* __restrict__ a_dst,
                                 int n) {
  int tid = blockIdx.x * blockDim.x + threadIdx.x;
  int node = tid >> 2;
  int q = tid & 3;
  if (node >= n) return;
  int h = q >> 1;
  const float4* xwv = reinterpret_cast<const float4*>(XW + (size_t)node * 128 + q * 32);
  const float4* asv = reinterpret_cast<const float4*>(att_s + q * 32);
  const float4* adv = reinterpret_cast<const float4*>(att_d + q * 32);
  float ss = 0.f, sd = 0.f;
#pragma unroll
  for (int i = 0; i < 8; ++i) {
    float4 v = xwv[i]; float4 a = asv[i]; float4 d = adv[i];
    ss += v.x * a.x + v.y * a.y + v.z * a.z + v.w * a.w;
    sd += v.x * d.x + v.y * d.y + v.z * d.z + v.w * d.w;
  }
  ss += __shfl_xor(ss, 1);
  sd += __shfl_xor(sd, 1);
  if ((q & 1) == 0) {
    a_src[node * 2 + h] = ss;
    a_dst[node * 2 + h] = sd;
  }
}

// --- CSR build (once; edges identical for both layers) ---
__global__ void hist_kernel(const void* __restrict__ edges, const int* __restrict__ isI32,
                            int E, int* __restrict__ deg) {
  int e = blockIdx.x * blockDim.x + threadIdx.x;
  if (e >= E) return;
  int i32 = *isI32;
  int s, d;
  load_edge(edges, i32, E, e, &s, &d);
  atomicAdd(&deg[d], 1);
}

// Parallel segment allocator: per-wave prefix sum + 1 atomic per wave.
// Segment starts need not be monotone in node id -- gat_node only needs
// a contiguous [offs, offs+deg) range per node.
__global__ void offsets_kernel(const int* __restrict__ deg, int* __restrict__ offs,
                               int* __restrict__ cursor, int* __restrict__ total, int n) {
  int t = blockIdx.x * blockDim.x + threadIdx.x;
  int lane = threadIdx.x & 63;
  int d = (t < n) ? deg[t] : 0;
  int pre = d;
#pragma unroll
  for (int sh = 1; sh < 64; sh <<= 1) {
    int v = __shfl_up(pre, sh);
    if (lane >= sh) pre += v;
  }
  int wavesum = __shfl(pre, 63);
  int base = 0;
  if (lane == 63) base = atomicAdd(total, wavesum);
  base = __shfl(base, 63);
  int start = base + pre - d;
  if (t < n) {
    offs[t] = start;
    cursor[t] = start;
  }
}

__global__ void scatter_kernel(const void* __restrict__ edges, const int* __restrict__ isI32,
                               int E, int* __restrict__ cursor, int* __restrict__ csr) {
  int e = blockIdx.x * blockDim.x + threadIdx.x;
  if (e >= E) return;
  int i32 = *isI32;
  int s, d;
  load_edge(edges, i32, E, e, &s, &d);
  int pos = atomicAdd(&cursor[d], 1);
  csr[pos] = s;
}

// --- Fused per-node GAT: softmax over in-neighbors + weighted gather + bias + ELU.
// One 64-lane wave per node; lane owns output cols [2*lane, 2*lane+1].
__global__ __launch_bounds__(256) void gat_node_kernel(
    const float* __restrict__ XW, const float* __restrict__ a_src,
    const float* __restrict__ a_dst, const int* __restrict__ offs,
    const int* __restrict__ degarr, const int* __restrict__ csr,
    const float* __restrict__ bias, float* __restrict__ out, int n) {
  const int node = (int)((blockIdx.x * (unsigned)blockDim.x + threadIdx.x) >> 6);
  const int lane = threadIdx.x & 63;
  if (node >= n) return;
  const int off = offs[node];
  const int deg = degarr[node];
  const float2 aself = reinterpret_cast<const float2*>(a_src)[node];
  const float2 ad = reinterpret_cast<const float2*>(a_dst)[node];

  // Phase A: running max of a_src over in-neighbors (seed = self-loop).
  // lrelu is monotone, so amax = lrelu(a_dst + max a_src).
  float m0 = aself.x, m1 = aself.y;
  int s_c = 0;
  float v0_c = NEG_BIG, v1_c = NEG_BIG;
  for (int base = 0; base < deg; base += 64) {
    int i = base + lane;
    int s = 0;
    float v0 = NEG_BIG, v1 = NEG_BIG;
    if (i < deg) {
      s = csr[off + i];
      float2 a = reinterpret_cast<const float2*>(a_src)[s];
      v0 = a.x; v1 = a.y;
    }
    if (base == 0) { s_c = s; v0_c = v0; v1_c = v1; }
    m0 = fmaxf(m0, v0);
    m1 = fmaxf(m1, v1);
  }
#pragma unroll
  for (int d = 32; d; d >>= 1) {
    m0 = fmaxf(m0, __shfl_xor(m0, d));
    m1 = fmaxf(m1, __shfl_xor(m1, d));
  }
  const float am0 = lrelu(ad.x + m0), am1 = lrelu(ad.y + m1);

  // Phase B: softmax denominator.
  float sum0 = 0.f, sum1 = 0.f;
  for (int base = 0; base < deg; base += 64) {
    int i = base + lane;
    float v0 = v0_c, v1 = v1_c;
    if (base != 0) {
      if (i < deg) {
        float2 a = reinterpret_cast<const float2*>(a_src)[csr[off + i]];
        v0 = a.x; v1 = a.y;
      } else { v0 = NEG_BIG; v1 = NEG_BIG; }
    }
    if (i < deg) {
      sum0 += expf(lrelu(v0 + ad.x) - am0);
      sum1 += expf(lrelu(v1 + ad.y) - am1);
    }
  }
#pragma unroll
  for (int d = 32; d; d >>= 1) {
    sum0 += __shfl_xor(sum0, d);
    sum1 += __shfl_xor(sum1, d);
  }
  const float es0 = expf(lrelu(aself.x + ad.x) - am0);
  const float es1 = expf(lrelu(aself.y + ad.y) - am1);
  sum0 += es0; sum1 += es1;
  const float r0 = 1.f / (sum0 + SM_EPS);
  const float r1 = 1.f / (sum1 + SM_EPS);

  // Phase C: out[node] = bias + coef_self*xw[node] + sum coef_e*xw[src_e]
  const float selfc = (lane < 32) ? es0 * r0 : es1 * r1;
  const float2 xself = reinterpret_cast<const float2*>(XW)[(size_t)node * 64 + lane];
  const float2 b = reinterpret_cast<const float2*>(bias)[lane];
  float accx = b.x + selfc * xself.x;
  float accy = b.y + selfc * xself.y;

  for (int base = 0; base < deg; base += 64) {
    int i = base + lane;
    int s = s_c;
    float c0, c1;
    if (base == 0) {
      c0 = expf(lrelu(v0_c + ad.x) - am0) * r0;
      c1 = expf(lrelu(v1_c + ad.y) - am1) * r1;
    } else if (i < deg) {
      s = csr[off + i];
      float2 a = reinterpret_cast<const float2*>(a_src)[s];
      c0 = expf(lrelu(a.x + ad.x) - am0) * r0;
      c1 = expf(lrelu(a.y + ad.y) - am1) * r1;
    } else { s = 0; c0 = 0.f; c1 = 0.f; }
    const int cnt = min(64, deg - base);
    for (int j = 0; j < cnt; ++j) {
      int sj = __shfl(s, j);
      float cf0 = __shfl(c0, j);
      float cf1 = __shfl(c1, j);
      float cf = (lane < 32) ? cf0 : cf1;
      float2 v = reinterpret_cast<const float2*>(XW)[(size_t)sj * 64 + lane];
      accx += cf * v.x;
      accy += cf * v.y;
    }
  }

  // ELU (applied after both layers) + store
  accx = accx > 0.f ? accx : expm1f(accx);
  accy = accy > 0.f ? accy : expm1f(accy);
  reinterpret_cast<float2*>(out)[(size_t)node * 64 + lane] = make_float2(accx, accy);
}

extern "C" void kernel_launch(void* const* d_in, const int* in_sizes, int n_in,
                              void* d_out, int out_size, void* d_ws, size_t ws_size,
                              hipStream_t stream) {
  const float* x    = (const float*)d_in[0];
  const void* edges = d_in[1];
  const float* W0  = (const float*)d_in[2];
  const float* as0 = (const float*)d_in[3];
  const float* ad0 = (const float*)d_in[4];
  const float* b0  = (const float*)d_in[5];
  const float* W1  = (const float*)d_in[6];
  const float* as1 = (const float*)d_in[7];
  const float* ad1 = (const float*)d_in[8];
  const float* b1  = (const float*)d_in[9];
  float* out = (float*)d_out;

  const int n = in_sizes[0] / 128;
  const int E = in_sizes[1] / 2;

  float* xw    = (float*)d_ws;
  float* hbuf  = xw + (size_t)n * 128;
  float* a_src = hbuf + (size_t)n * 128;
  float* a_dst = a_src + 2 * (size_t)n;
  int* offs    = (int*)(a_dst + 2 * (size_t)n);  // n
  int* deg     = offs + n;                       // n
  int* cursor  = deg + n;                        // n
  int* csr     = cursor + n;                     // E
  int* flag    = csr + E;                        // 1
  int* total   = flag + 1;                       // 1

  hipMemsetAsync(flag, 0, 2 * sizeof(int), stream);
  hipMemsetAsync(deg, 0, (size_t)n * sizeof(int), stream);

  int dcount = E < 4096 ? E : 4096;
  detect_i32_kernel<<<(dcount + 255) / 256, 256, 0, stream>>>(
      (const unsigned long long*)edges, dcount, (unsigned long long)n, flag);

  // CSR build (edges shared by both layers)
  hist_kernel<<<(E + 255) / 256, 256, 0, stream>>>(edges, flag, E, deg);
  offsets_kernel<<<(n + 255) / 256, 256, 0, stream>>>(deg, offs, cursor, total, n);
  scatter_kernel<<<(E + 255) / 256, 256, 0, stream>>>(edges, flag, E, cursor, csr);

  const float* in_feat = x;
  for (int layer = 0; layer < 2; ++layer) {
    const float* W   = layer ? W1 : W0;
    const float* as_ = layer ? as1 : as0;
    const float* ad_ = layer ? ad1 : ad0;
    const float* bs  = layer ? b1 : b0;
    float* acc = layer ? out : hbuf;

    gemm_xw_kernel<<<(n + 63) / 64, 256, 0, stream>>>(in_feat, W, xw, n);
    attn_node_kernel<<<(n * 4 + 255) / 256, 256, 0, stream>>>(xw, as_, ad_, a_src, a_dst, n);
    gat_node_kernel<<<(n + 3) / 4, 256, 0, stream>>>(xw, a_src, a_dst, offs, deg, csr, bs, acc, n);

    in_feat = hbuf;
  }
}

// Round 5
// 398.116 us; speedup vs baseline: 8.1412x; 1.0785x over previous
//
#include <hip/hip_runtime.h>

constexpr float NEG_SLOPE = 0.2f;
constexpr float SM_EPS = 1e-16f;
#define NEG_BIG (-3.0e38f)

__device__ __forceinline__ float lrelu(float x) { return x > 0.f ? x : NEG_SLOPE * x; }

__device__ __forceinline__ void load_edge(const void* edges, int i32, int E, int e,
                                          int* s, int* d) {
  if (i32) {
    *s = ((const int*)edges)[e];
    *d = ((const int*)edges)[E + e];
  } else {
    *s = (int)((const long long*)edges)[e];
    *d = (int)((const long long*)edges)[E + e];
  }
}

// Detect whether edge buffer is int32 (flag=1) or int64 (flag=0).
__global__ void detect_i32_kernel(const unsigned long long* __restrict__ e, int count,
                                  unsigned long long n, int* flag) {
  int t = blockIdx.x * blockDim.x + threadIdx.x;
  if (t < count && e[t] >= n) atomicOr(flag, 1);
}

// XW[row][o] = sum_k X[row][k] * W[o][k]   (x @ W.T).
// X tile (64 rows, 32 KB) in LDS; W read directly from global (L1/L2-resident).
__global__ __launch_bounds__(256, 4) void gemm_xw_kernel(
    const float* __restrict__ X, const float* __restrict__ W,
    float* __restrict__ XW, int n) {
  __shared__ float xs[64 * 128];    // xs[r][k]
  const int tid = threadIdx.x;
  const int row0 = blockIdx.x * 64;

#pragma unroll
  for (int i = 0; i < 8; ++i) {
    int f = tid + i * 256;                 // [0,2048) float4s of x tile
    int r = f >> 5;
    int c4 = f & 31;
    int row = row0 + r;
    float4 v = make_float4(0.f, 0.f, 0.f, 0.f);
    if (row < n) v = reinterpret_cast<const float4*>(X)[(size_t)row * 32 + c4];
    reinterpret_cast<float4*>(xs)[f] = v;
  }
  __syncthreads();

  const int tc = tid & 31;   // output cols tc*4 .. tc*4+3
  const int tr = tid >> 5;   // rows tr*8 .. tr*8+7
  float acc[8][4];
#pragma unroll
  for (int i = 0; i < 8; ++i)
#pragma unroll
    for (int j = 0; j < 4; ++j) acc[i][j] = 0.f;

#pragma unroll 2
  for (int k = 0; k < 128; k += 4) {
    // w[j][kk] = W[tc*4+j][k+kk]
    float4 w[4];
#pragma unroll
    for (int j = 0; j < 4; ++j)
      w[j] = *reinterpret_cast<const float4*>(&W[(size_t)(tc * 4 + j) * 128 + k]);
#pragma unroll
    for (int i = 0; i < 8; ++i) {
      float4 a = *reinterpret_cast<const float4*>(&xs[(tr * 8 + i) * 128 + k]);
#pragma unroll
      for (int j = 0; j < 4; ++j)
        acc[i][j] += a.x * w[j].x + a.y * w[j].y + a.z * w[j].z + a.w * w[j].w;
    }
  }

#pragma unroll
  for (int i = 0; i < 8; ++i) {
    int row = row0 + tr * 8 + i;
    if (row < n) {
      float4 o4 = make_float4(acc[i][0], acc[i][1], acc[i][2], acc[i][3]);
      reinterpret_cast<float4*>(XW)[(size_t)row * 32 + tc] = o4;
    }
  }
}

// a_src/a_dst per (node, head). 4 threads per node, 32 cols each.
__global__ void attn_node_kernel(const float* __restrict__ XW,
                                 const float* __restrict__ att_s,
                                 const float* __restrict__ att_d,
                                 float* __restrict__ a_src, float* __restrict__ a_dst,
                                 int n) {
  int tid = blockIdx.x * blockDim.x + threadIdx.x;
  int node = tid >> 2;
  int q = tid & 3;
  if (node >= n) return;
  int h = q >> 1;
  const float4* xwv = reinterpret_cast<const float4*>(XW + (size_t)node * 128 + q * 32);
  const float4* asv = reinterpret_cast<const float4*>(att_s + q * 32);
  const float4* adv = reinterpret_cast<const float4*>(att_d + q * 32);
  float ss = 0.f, sd = 0.f;
#pragma unroll
  for (int i = 0; i < 8; ++i) {
    float4 v = xwv[i]; float4 a = asv[i]; float4 d = adv[i];
    ss += v.x * a.x + v.y * a.y + v.z * a.z + v.w * a.w;
    sd += v.x * d.x + v.y * d.y + v.z * d.z + v.w * d.w;
  }
  ss += __shfl_xor(ss, 1);
  sd += __shfl_xor(sd, 1);
  if ((q & 1) == 0) {
    a_src[node * 2 + h] = ss;
    a_dst[node * 2 + h] = sd;
  }
}

// --- CSR build (once; edges identical for both layers) ---
__global__ void hist_kernel(const void* __restrict__ edges, const int* __restrict__ isI32,
                            int E, int* __restrict__ deg) {
  int e = blockIdx.x * blockDim.x + threadIdx.x;
  if (e >= E) return;
  int i32 = *isI32;
  int s, d;
  load_edge(edges, i32, E, e, &s, &d);
  atomicAdd(&deg[d], 1);
}

// Parallel segment allocator: per-wave prefix sum + 1 atomic per wave.
__global__ void offsets_kernel(const int* __restrict__ deg, int* __restrict__ offs,
                               int* __restrict__ cursor, int* __restrict__ total, int n) {
  int t = blockIdx.x * blockDim.x + threadIdx.x;
  int lane = threadIdx.x & 63;
  int d = (t < n) ? deg[t] : 0;
  int pre = d;
#pragma unroll
  for (int sh = 1; sh < 64; sh <<= 1) {
    int v = __shfl_up(pre, sh);
    if (lane >= sh) pre += v;
  }
  int wavesum = __shfl(pre, 63);
  int base = 0;
  if (lane == 63) base = atomicAdd(total, wavesum);
  base = __shfl(base, 63);
  int start = base + pre - d;
  if (t < n) {
    offs[t] = start;
    cursor[t] = start;
  }
}

__global__ void scatter_kernel(const void* __restrict__ edges, const int* __restrict__ isI32,
                               int E, int* __restrict__ cursor, int* __restrict__ csr) {
  int e = blockIdx.x * blockDim.x + threadIdx.x;
  if (e >= E) return;
  int i32 = *isI32;
  int s, d;
  load_edge(edges, i32, E, e, &s, &d);
  int pos = atomicAdd(&cursor[d], 1);
  csr[pos] = s;
}

// --- Fused per-node GAT: softmax over in-neighbors + weighted gather + bias + ELU.
// One 64-lane wave per node. Phase C: two 32-lane halves each gather one edge
// per step. All shuffle sources stay ACTIVE: uniform jb loop, predicated cf.
__global__ __launch_bounds__(256) void gat_node_kernel(
    const float* __restrict__ XW, const float* __restrict__ a_src,
    const float* __restrict__ a_dst, const int* __restrict__ offs,
    const int* __restrict__ degarr, const int* __restrict__ csr,
    const float* __restrict__ bias, float* __restrict__ out, int n) {
  const int node = (int)((blockIdx.x * (unsigned)blockDim.x + threadIdx.x) >> 6);
  const int lane = threadIdx.x & 63;
  if (node >= n) return;
  const int off = offs[node];
  const int deg = degarr[node];
  const float2 aself = reinterpret_cast<const float2*>(a_src)[node];
  const float2 ad = reinterpret_cast<const float2*>(a_dst)[node];

  // Phase A: running max of a_src over in-neighbors (seed = self-loop).
  // lrelu monotone -> amax = lrelu(a_dst + max a_src).
  float m0 = aself.x, m1 = aself.y;
  int s_c = 0;
  float v0_c = NEG_BIG, v1_c = NEG_BIG;
  for (int base = 0; base < deg; base += 64) {
    int i = base + lane;
    int s = 0;
    float v0 = NEG_BIG, v1 = NEG_BIG;
    if (i < deg) {
      s = csr[off + i];
      float2 a = reinterpret_cast<const float2*>(a_src)[s];
      v0 = a.x; v1 = a.y;
    }
    if (base == 0) { s_c = s; v0_c = v0; v1_c = v1; }
    m0 = fmaxf(m0, v0);
    m1 = fmaxf(m1, v1);
  }
#pragma unroll
  for (int d = 32; d; d >>= 1) {
    m0 = fmaxf(m0, __shfl_xor(m0, d));
    m1 = fmaxf(m1, __shfl_xor(m1, d));
  }
  const float am0 = lrelu(ad.x + m0), am1 = lrelu(ad.y + m1);

  // Phase B: softmax denominator.
  float sum0 = 0.f, sum1 = 0.f;
  for (int base = 0; base < deg; base += 64) {
    int i = base + lane;
    float v0 = v0_c, v1 = v1_c;
    if (base != 0) {
      if (i < deg) {
        float2 a = reinterpret_cast<const float2*>(a_src)[csr[off + i]];
        v0 = a.x; v1 = a.y;
      } else { v0 = NEG_BIG; v1 = NEG_BIG; }
    }
    if (i < deg) {
      sum0 += expf(lrelu(v0 + ad.x) - am0);
      sum1 += expf(lrelu(v1 + ad.y) - am1);
    }
  }
#pragma unroll
  for (int d = 32; d; d >>= 1) {
    sum0 += __shfl_xor(sum0, d);
    sum1 += __shfl_xor(sum1, d);
  }
  const float es0 = expf(lrelu(aself.x + ad.x) - am0);
  const float es1 = expf(lrelu(aself.y + ad.y) - am1);
  sum0 += es0; sum1 += es1;
  const float r0 = 1.f / (sum0 + SM_EPS);
  const float r1 = 1.f / (sum1 + SM_EPS);

  // Phase C: half-wave gather. lane -> half hw, col slot c (float4), head h.
  const int hw = lane >> 5;
  const int c = lane & 31;
  const int h = c >> 4;
  float4 acc4 = make_float4(0.f, 0.f, 0.f, 0.f);
  if (hw == 0) {
    const float selfc = (h == 0) ? es0 * r0 : es1 * r1;
    float4 b4 = reinterpret_cast<const float4*>(bias)[c];
    float4 xs4 = reinterpret_cast<const float4*>(XW)[(size_t)node * 32 + c];
    acc4 = make_float4(b4.x + selfc * xs4.x, b4.y + selfc * xs4.y,
                       b4.z + selfc * xs4.z, b4.w + selfc * xs4.w);
  }

  for (int base = 0; base < deg; base += 64) {
    int i = base + lane;
    int s = s_c;
    float c0, c1;
    if (base == 0) {
      c0 = expf(lrelu(v0_c + ad.x) - am0) * r0;
      c1 = expf(lrelu(v1_c + ad.y) - am1) * r1;
    } else if (i < deg) {
      s = csr[off + i];
      float2 a = reinterpret_cast<const float2*>(a_src)[s];
      c0 = expf(lrelu(a.x + ad.x) - am0) * r0;
      c1 = expf(lrelu(a.y + ad.y) - am1) * r1;
    } else { s = 0; c0 = 0.f; c1 = 0.f; }
    const int cnt = min(64, deg - base);
    // Uniform trip count across the wave; predicate the odd tail so every
    // __shfl executes with ALL source lanes active (no inactive-lane reads).
    for (int jb = 0; jb < cnt; jb += 2) {
      int j = jb + hw;
      int jc = j < cnt ? j : 0;
      int sj = __shfl(s, jc);
      float cf0 = __shfl(c0, jc);
      float cf1 = __shfl(c1, jc);
      float cf = (h == 0) ? cf0 : cf1;
      if (j >= cnt) cf = 0.f;
      float4 v = reinterpret_cast<const float4*>(XW)[(size_t)sj * 32 + c];
      acc4.x += cf * v.x;
      acc4.y += cf * v.y;
      acc4.z += cf * v.z;
      acc4.w += cf * v.w;
    }
  }

  // combine halves
  acc4.x += __shfl_xor(acc4.x, 32);
  acc4.y += __shfl_xor(acc4.y, 32);
  acc4.z += __shfl_xor(acc4.z, 32);
  acc4.w += __shfl_xor(acc4.w, 32);

  if (hw == 0) {
    // ELU + store
    acc4.x = acc4.x > 0.f ? acc4.x : expm1f(acc4.x);
    acc4.y = acc4.y > 0.f ? acc4.y : expm1f(acc4.y);
    acc4.z = acc4.z > 0.f ? acc4.z : expm1f(acc4.z);
    acc4.w = acc4.w > 0.f ? acc4.w : expm1f(acc4.w);
    reinterpret_cast<float4*>(out)[(size_t)node * 32 + c] = acc4;
  }
}

extern "C" void kernel_launch(void* const* d_in, const int* in_sizes, int n_in,
                              void* d_out, int out_size, void* d_ws, size_t ws_size,
                              hipStream_t stream) {
  const float* x    = (const float*)d_in[0];
  const void* edges = d_in[1];
  const float* W0  = (const float*)d_in[2];
  const float* as0 = (const float*)d_in[3];
  const float* ad0 = (const float*)d_in[4];
  const float* b0  = (const float*)d_in[5];
  const float* W1  = (const float*)d_in[6];
  const float* as1 = (const float*)d_in[7];
  const float* ad1 = (const float*)d_in[8];
  const float* b1  = (const float*)d_in[9];
  float* out = (float*)d_out;

  const int n = in_sizes[0] / 128;
  const int E = in_sizes[1] / 2;

  float* xw    = (float*)d_ws;
  float* hbuf  = xw + (size_t)n * 128;
  float* a_src = hbuf + (size_t)n * 128;
  float* a_dst = a_src + 2 * (size_t)n;
  int* offs    = (int*)(a_dst + 2 * (size_t)n);  // n
  int* deg     = offs + n;                       // n
  int* cursor  = deg + n;                        // n
  int* csr     = cursor + n;                     // E
  int* flag    = csr + E;                        // 1
  int* total   = flag + 1;                       // 1

  hipMemsetAsync(flag, 0, 2 * sizeof(int), stream);
  hipMemsetAsync(deg, 0, (size_t)n * sizeof(int), stream);

  int dcount = E < 4096 ? E : 4096;
  detect_i32_kernel<<<(dcount + 255) / 256, 256, 0, stream>>>(
      (const unsigned long long*)edges, dcount, (unsigned long long)n, flag);

  // CSR build (edges shared by both layers)
  hist_kernel<<<(E + 255) / 256, 256, 0, stream>>>(edges, flag, E, deg);
  offsets_kernel<<<(n + 255) / 256, 256, 0, stream>>>(deg, offs, cursor, total, n);
  scatter_kernel<<<(E + 255) / 256, 256, 0, stream>>>(edges, flag, E, cursor, csr);

  const float* in_feat = x;
  for (int layer = 0; layer < 2; ++layer) {
    const float* W   = layer ? W1 : W0;
    const float* as_ = layer ? as1 : as0;
    const float* ad_ = layer ? ad1 : ad0;
    const float* bs  = layer ? b1 : b0;
    float* acc = layer ? out : hbuf;

    gemm_xw_kernel<<<(n + 63) / 64, 256, 0, stream>>>(in_feat, W, xw, n);
    attn_node_kernel<<<(n * 4 + 255) / 256, 256, 0, stream>>>(xw, as_, ad_, a_src, a_dst, n);
    gat_node_kernel<<<(n + 3) / 4, 256, 0, stream>>>(xw, a_src, a_dst, offs, deg, csr, bs, acc, n);

    in_feat = hbuf;
  }
}

// Round 6
// 325.499 us; speedup vs baseline: 9.9574x; 1.2231x over previous
//
#include <hip/hip_runtime.h>

constexpr float NEG_SLOPE = 0.2f;
constexpr float SM_EPS = 1e-16f;
#define NEG_BIG (-3.0e38f)

typedef __bf16 bf16x8 __attribute__((ext_vector_type(8)));
typedef float f32x4 __attribute__((ext_vector_type(4)));

__device__ __forceinline__ float lrelu(float x) { return x > 0.f ? x : NEG_SLOPE * x; }

// f32 -> bf16 round-nearest-even (inputs are finite; no NaN path needed)
__device__ __forceinline__ unsigned short f2bf(float f) {
  unsigned u = __float_as_uint(f);
  unsigned r = u + 0x7FFFu + ((u >> 16) & 1u);
  return (unsigned short)(r >> 16);
}
__device__ __forceinline__ float bf2f(unsigned short h) {
  return __uint_as_float((unsigned)h << 16);
}

__device__ __forceinline__ void load_edge(const void* edges, int i32, int E, int e,
                                          int* s, int* d) {
  if (i32) {
    *s = ((const int*)edges)[e];
    *d = ((const int*)edges)[E + e];
  } else {
    *s = (int)((const long long*)edges)[e];
    *d = (int)((const long long*)edges)[E + e];
  }
}

// Detect whether edge buffer is int32 (flag=1) or int64 (flag=0).
__global__ void detect_i32_kernel(const unsigned long long* __restrict__ e, int count,
                                  unsigned long long n, int* flag) {
  int t = blockIdx.x * blockDim.x + threadIdx.x;
  if (t < count && e[t] >= n) atomicOr(flag, 1);
}

// Split W (128x128 f32) into bf16 hi/lo once per layer.
__global__ void wconv_kernel(const float* __restrict__ W, unsigned short* __restrict__ whi,
                             unsigned short* __restrict__ wlo) {
  int t = blockIdx.x * blockDim.x + threadIdx.x;
  if (t >= 128 * 128) return;
  float w = W[t];
  unsigned short h = f2bf(w);
  whi[t] = h;
  wlo[t] = f2bf(w - bf2f(h));
}

// XW = X @ W.T via split-bf16 MFMA: X=hi+lo, W=hi+lo;
// XW ~= Ahi*Bhi + Ahi*Blo + Alo*Bhi (f32 accumulate; lo*lo ~ 2^-18 dropped).
// Block: 128 rows; 4 waves x 32 rows; full N=128.
__global__ __launch_bounds__(256, 2) void gemm_mfma_kernel(
    const float* __restrict__ X, const unsigned short* __restrict__ whi,
    const unsigned short* __restrict__ wlo, float* __restrict__ XW, int n) {
  __shared__ unsigned short xh[128 * 136];   // +8 bf16 row pad: 2-way-free banks
  __shared__ unsigned short xl[128 * 136];
  const int tid = threadIdx.x;
  const int row0 = blockIdx.x * 128;

  // Stage X tile, converting f32 -> (hi,lo) bf16.
#pragma unroll
  for (int i = 0; i < 16; ++i) {
    int f = tid + i * 256;                 // [0,4096) float4s
    int r = f >> 5, c4 = f & 31;
    int row = row0 + r;
    float4 v = make_float4(0.f, 0.f, 0.f, 0.f);
    if (row < n) v = reinterpret_cast<const float4*>(X)[(size_t)row * 32 + c4];
    ushort4 h, l;
    h.x = f2bf(v.x); l.x = f2bf(v.x - bf2f(h.x));
    h.y = f2bf(v.y); l.y = f2bf(v.y - bf2f(h.y));
    h.z = f2bf(v.z); l.z = f2bf(v.z - bf2f(h.z));
    h.w = f2bf(v.w); l.w = f2bf(v.w - bf2f(h.w));
    *reinterpret_cast<ushort4*>(&xh[r * 136 + c4 * 4]) = h;
    *reinterpret_cast<ushort4*>(&xl[r * 136 + c4 * 4]) = l;
  }
  __syncthreads();

  const int lane = tid & 63;
  const int wv = tid >> 6;       // wave id: rows wv*32 .. wv*32+31
  const int wrow = wv * 32;
  const int lm = lane & 15;      // A row / B col / D col
  const int lk = lane >> 4;      // k-group (A/B), row-group (D)

#pragma unroll
  for (int nt = 0; nt < 8; ++nt) {
    const int n0 = nt * 16;
    bf16x8 bh[4], bl[4];
#pragma unroll
    for (int ks = 0; ks < 4; ++ks) {
      int baddr = (n0 + lm) * 128 + ks * 32 + lk * 8;
      bh[ks] = *reinterpret_cast<const bf16x8*>(&whi[baddr]);
      bl[ks] = *reinterpret_cast<const bf16x8*>(&wlo[baddr]);
    }
#pragma unroll
    for (int rt = 0; rt < 2; ++rt) {
      f32x4 acc = {0.f, 0.f, 0.f, 0.f};
#pragma unroll
      for (int ks = 0; ks < 4; ++ks) {
        int aoff = (wrow + rt * 16 + lm) * 136 + ks * 32 + lk * 8;
        bf16x8 ah = *reinterpret_cast<const bf16x8*>(&xh[aoff]);
        bf16x8 al = *reinterpret_cast<const bf16x8*>(&xl[aoff]);
        acc = __builtin_amdgcn_mfma_f32_16x16x32_bf16(ah, bh[ks], acc, 0, 0, 0);
        acc = __builtin_amdgcn_mfma_f32_16x16x32_bf16(ah, bl[ks], acc, 0, 0, 0);
        acc = __builtin_amdgcn_mfma_f32_16x16x32_bf16(al, bh[ks], acc, 0, 0, 0);
      }
      const int gcol = n0 + lm;
      const int grow = row0 + wrow + rt * 16 + lk * 4;
#pragma unroll
      for (int j = 0; j < 4; ++j) {
        if (grow + j < n) XW[(size_t)(grow + j) * 128 + gcol] = acc[j];
      }
    }
  }
}

// a_src/a_dst per (node, head). 4 threads per node, 32 cols each.
__global__ void attn_node_kernel(const float* __restrict__ XW,
                                 const float* __restrict__ att_s,
                                 const float* __restrict__ att_d,
                                 float* __restrict__ a_src, float* __restrict__ a_dst,
                                 int n) {
  int tid = blockIdx.x * blockDim.x + threadIdx.x;
  int node = tid >> 2;
  int q = tid & 3;
  if (node >= n) return;
  int h = q >> 1;
  const float4* xwv = reinterpret_cast<const float4*>(XW + (size_t)node * 128 + q * 32);
  const float4* asv = reinterpret_cast<const float4*>(att_s + q * 32);
  const float4* adv = reinterpret_cast<const float4*>(att_d + q * 32);
  float ss = 0.f, sd = 0.f;
#pragma unroll
  for (int i = 0; i < 8; ++i) {
    float4 v = xwv[i]; float4 a = asv[i]; float4 d = adv[i];
    ss += v.x * a.x + v.y * a.y + v.z * a.z + v.w * a.w;
    sd += v.x * d.x + v.y * d.y + v.z * d.z + v.w * d.w;
  }
  ss += __shfl_xor(ss, 1);
  sd += __shfl_xor(sd, 1);
  if ((q & 1) == 0) {
    a_src[node * 2 + h] = ss;
    a_dst[node * 2 + h] = sd;
  }
}

// --- CSR build (once; edges identical for both layers) ---
__global__ void hist_kernel(const void* __restrict__ edges, const int* __restrict__ isI32,
                            int E, int* __restrict__ deg) {
  int e = blockIdx.x * blockDim.x + threadIdx.x;
  if (e >= E) return;
  int i32 = *isI32;
  int s, d;
  load_edge(edges, i32, E, e, &s, &d);
  atomicAdd(&deg[d], 1);
}

// Parallel segment allocator: per-wave prefix sum + 1 atomic per wave.
__global__ void offsets_kernel(const int* __restrict__ deg, int* __restrict__ offs,
                               int* __restrict__ cursor, int* __restrict__ total, int n) {
  int t = blockIdx.x * blockDim.x + threadIdx.x;
  int lane = threadIdx.x & 63;
  int d = (t < n) ? deg[t] : 0;
  int pre = d;
#pragma unroll
  for (int sh = 1; sh < 64; sh <<= 1) {
    int v = __shfl_up(pre, sh);
    if (lane >= sh) pre += v;
  }
  int wavesum = __shfl(pre, 63);
  int base = 0;
  if (lane == 63) base = atomicAdd(total, wavesum);
  base = __shfl(base, 63);
  int start = base + pre - d;
  if (t < n) {
    offs[t] = start;
    cursor[t] = start;
  }
}

__global__ void scatter_kernel(const void* __restrict__ edges, const int* __restrict__ isI32,
                               int E, int* __restrict__ cursor, int* __restrict__ csr) {
  int e = blockIdx.x * blockDim.x + threadIdx.x;
  if (e >= E) return;
  int i32 = *isI32;
  int s, d;
  load_edge(edges, i32, E, e, &s, &d);
  int pos = atomicAdd(&cursor[d], 1);
  csr[pos] = s;
}

// --- Fused per-node GAT: softmax over in-neighbors + weighted gather + bias + ELU.
// One 64-lane wave per node. Phase C: two 32-lane halves each gather one edge
// per step. All shuffle sources stay ACTIVE: uniform jb loop, predicated cf.
__global__ __launch_bounds__(256) void gat_node_kernel(
    const float* __restrict__ XW, const float* __restrict__ a_src,
    const float* __restrict__ a_dst, const int* __restrict__ offs,
    const int* __restrict__ degarr, const int* __restrict__ csr,
    const float* __restrict__ bias, float* __restrict__ out, int n) {
  const int node = (int)((blockIdx.x * (unsigned)blockDim.x + threadIdx.x) >> 6);
  const int lane = threadIdx.x & 63;
  if (node >= n) return;
  const int off = offs[node];
  const int deg = degarr[node];
  const float2 aself = reinterpret_cast<const float2*>(a_src)[node];
  const float2 ad = reinterpret_cast<const float2*>(a_dst)[node];

  // Phase A: running max of a_src over in-neighbors (seed = self-loop).
  float m0 = aself.x, m1 = aself.y;
  int s_c = 0;
  float v0_c = NEG_BIG, v1_c = NEG_BIG;
  for (int base = 0; base < deg; base += 64) {
    int i = base + lane;
    int s = 0;
    float v0 = NEG_BIG, v1 = NEG_BIG;
    if (i < deg) {
      s = csr[off + i];
      float2 a = reinterpret_cast<const float2*>(a_src)[s];
      v0 = a.x; v1 = a.y;
    }
    if (base == 0) { s_c = s; v0_c = v0; v1_c = v1; }
    m0 = fmaxf(m0, v0);
    m1 = fmaxf(m1, v1);
  }
#pragma unroll
  for (int d = 32; d; d >>= 1) {
    m0 = fmaxf(m0, __shfl_xor(m0, d));
    m1 = fmaxf(m1, __shfl_xor(m1, d));
  }
  const float am0 = lrelu(ad.x + m0), am1 = lrelu(ad.y + m1);

  // Phase B: softmax denominator.
  float sum0 = 0.f, sum1 = 0.f;
  for (int base = 0; base < deg; base += 64) {
    int i = base + lane;
    float v0 = v0_c, v1 = v1_c;
    if (base != 0) {
      if (i < deg) {
        float2 a = reinterpret_cast<const float2*>(a_src)[csr[off + i]];
        v0 = a.x; v1 = a.y;
      } else { v0 = NEG_BIG; v1 = NEG_BIG; }
    }
    if (i < deg) {
      sum0 += expf(lrelu(v0 + ad.x) - am0);
      sum1 += expf(lrelu(v1 + ad.y) - am1);
    }
  }
#pragma unroll
  for (int d = 32; d; d >>= 1) {
    sum0 += __shfl_xor(sum0, d);
    sum1 += __shfl_xor(sum1, d);
  }
  const float es0 = expf(lrelu(aself.x + ad.x) - am0);
  const float es1 = expf(lrelu(aself.y + ad.y) - am1);
  sum0 += es0; sum1 += es1;
  const float r0 = 1.f / (sum0 + SM_EPS);
  const float r1 = 1.f / (sum1 + SM_EPS);

  // Phase C: half-wave gather. lane -> half hw, col slot c (float4), head h.
  const int hw = lane >> 5;
  const int c = lane & 31;
  const int h = c >> 4;
  float4 acc4 = make_float4(0.f, 0.f, 0.f, 0.f);
  if (hw == 0) {
    const float selfc = (h == 0) ? es0 * r0 : es1 * r1;
    float4 b4 = reinterpret_cast<const float4*>(bias)[c];
    float4 xs4 = reinterpret_cast<const float4*>(XW)[(size_t)node * 32 + c];
    acc4 = make_float4(b4.x + selfc * xs4.x, b4.y + selfc * xs4.y,
                       b4.z + selfc * xs4.z, b4.w + selfc * xs4.w);
  }

  for (int base = 0; base < deg; base += 64) {
    int i = base + lane;
    int s = s_c;
    float c0, c1;
    if (base == 0) {
      c0 = expf(lrelu(v0_c + ad.x) - am0) * r0;
      c1 = expf(lrelu(v1_c + ad.y) - am1) * r1;
    } else if (i < deg) {
      s = csr[off + i];
      float2 a = reinterpret_cast<const float2*>(a_src)[s];
      c0 = expf(lrelu(a.x + ad.x) - am0) * r0;
      c1 = expf(lrelu(a.y + ad.y) - am1) * r1;
    } else { s = 0; c0 = 0.f; c1 = 0.f; }
    const int cnt = min(64, deg - base);
    // Uniform trip count; predicate the tail so every __shfl has all
    // source lanes active.
    for (int jb = 0; jb < cnt; jb += 2) {
      int j = jb + hw;
      int jc = j < cnt ? j : 0;
      int sj = __shfl(s, jc);
      float cf0 = __shfl(c0, jc);
      float cf1 = __shfl(c1, jc);
      float cf = (h == 0) ? cf0 : cf1;
      if (j >= cnt) cf = 0.f;
      float4 v = reinterpret_cast<const float4*>(XW)[(size_t)sj * 32 + c];
      acc4.x += cf * v.x;
      acc4.y += cf * v.y;
      acc4.z += cf * v.z;
      acc4.w += cf * v.w;
    }
  }

  // combine halves
  acc4.x += __shfl_xor(acc4.x, 32);
  acc4.y += __shfl_xor(acc4.y, 32);
  acc4.z += __shfl_xor(acc4.z, 32);
  acc4.w += __shfl_xor(acc4.w, 32);

  if (hw == 0) {
    acc4.x = acc4.x > 0.f ? acc4.x : expm1f(acc4.x);
    acc4.y = acc4.y > 0.f ? acc4.y : expm1f(acc4.y);
    acc4.z = acc4.z > 0.f ? acc4.z : expm1f(acc4.z);
    acc4.w = acc4.w > 0.f ? acc4.w : expm1f(acc4.w);
    reinterpret_cast<float4*>(out)[(size_t)node * 32 + c] = acc4;
  }
}

extern "C" void kernel_launch(void* const* d_in, const int* in_sizes, int n_in,
                              void* d_out, int out_size, void* d_ws, size_t ws_size,
                              hipStream_t stream) {
  const float* x    = (const float*)d_in[0];
  const void* edges = d_in[1];
  const float* W0  = (const float*)d_in[2];
  const float* as0 = (const float*)d_in[3];
  const float* ad0 = (const float*)d_in[4];
  const float* b0  = (const float*)d_in[5];
  const float* W1  = (const float*)d_in[6];
  const float* as1 = (const float*)d_in[7];
  const float* ad1 = (const float*)d_in[8];
  const float* b1  = (const float*)d_in[9];
  float* out = (float*)d_out;

  const int n = in_sizes[0] / 128;
  const int E = in_sizes[1] / 2;

  float* xw    = (float*)d_ws;
  float* hbuf  = xw + (size_t)n * 128;
  float* a_src = hbuf + (size_t)n * 128;
  float* a_dst = a_src + 2 * (size_t)n;
  int* offs    = (int*)(a_dst + 2 * (size_t)n);  // n
  int* deg     = offs + n;                       // n
  int* cursor  = deg + n;                        // n
  int* csr     = cursor + n;                     // E
  int* flag    = csr + E;                        // 1
  int* total   = flag + 1;                       // 1
  unsigned short* whi = (unsigned short*)(total + 1);  // 16384
  unsigned short* wlo = whi + 128 * 128;               // 16384

  hipMemsetAsync(flag, 0, 2 * sizeof(int), stream);
  hipMemsetAsync(deg, 0, (size_t)n * sizeof(int), stream);

  int dcount = E < 4096 ? E : 4096;
  detect_i32_kernel<<<(dcount + 255) / 256, 256, 0, stream>>>(
      (const unsigned long long*)edges, dcount, (unsigned long long)n, flag);

  // CSR build (edges shared by both layers)
  hist_kernel<<<(E + 255) / 256, 256, 0, stream>>>(edges, flag, E, deg);
  offsets_kernel<<<(n + 255) / 256, 256, 0, stream>>>(deg, offs, cursor, total, n);
  scatter_kernel<<<(E + 255) / 256, 256, 0, stream>>>(edges, flag, E, cursor, csr);

  const float* in_feat = x;
  for (int layer = 0; layer < 2; ++layer) {
    const float* W   = layer ? W1 : W0;
    const float* as_ = layer ? as1 : as0;
    const float* ad_ = layer ? ad1 : ad0;
    const float* bs  = layer ? b1 : b0;
    float* acc = layer ? out : hbuf;

    wconv_kernel<<<64, 256, 0, stream>>>(W, whi, wlo);
    gemm_mfma_kernel<<<(n + 127) / 128, 256, 0, stream>>>(in_feat, whi, wlo, xw, n);
    attn_node_kernel<<<(n * 4 + 255) / 256, 256, 0, stream>>>(xw, as_, ad_, a_src, a_dst, n);
    gat_node_kernel<<<(n + 3) / 4, 256, 0, stream>>>(xw, a_src, a_dst, offs, deg, csr, bs, acc, n);

    in_feat = hbuf;
  }
}

// Round 7
// 283.095 us; speedup vs baseline: 11.4489x; 1.1498x over previous
//
#include <hip/hip_runtime.h>

constexpr float NEG_SLOPE = 0.2f;
constexpr float SM_EPS = 1e-16f;
#define NEG_BIG (-3.0e38f)

typedef __bf16 bf16x8 __attribute__((ext_vector_type(8)));
typedef float f32x4 __attribute__((ext_vector_type(4)));
typedef unsigned short ushort8 __attribute__((ext_vector_type(8)));

__device__ __forceinline__ float lrelu(float x) { return x > 0.f ? x : NEG_SLOPE * x; }

// f32 -> bf16 round-nearest-even (finite inputs)
__device__ __forceinline__ unsigned short f2bf(float f) {
  unsigned u = __float_as_uint(f);
  unsigned r = u + 0x7FFFu + ((u >> 16) & 1u);
  return (unsigned short)(r >> 16);
}
__device__ __forceinline__ float bf2f(unsigned short h) {
  return __uint_as_float((unsigned)h << 16);
}

__device__ __forceinline__ void load_edge(const void* edges, int i32, int E, int e,
                                          int* s, int* d) {
  if (i32) {
    *s = ((const int*)edges)[e];
    *d = ((const int*)edges)[E + e];
  } else {
    *s = (int)((const long long*)edges)[e];
    *d = (int)((const long long*)edges)[E + e];
  }
}

__global__ void detect_i32_kernel(const unsigned long long* __restrict__ e, int count,
                                  unsigned long long n, int* flag) {
  int t = blockIdx.x * blockDim.x + threadIdx.x;
  if (t < count && e[t] >= n) atomicOr(flag, 1);
}

// Split W (128x128 f32) into bf16 hi/lo once per layer.
__global__ void wconv_kernel(const float* __restrict__ W, unsigned short* __restrict__ whi,
                             unsigned short* __restrict__ wlo) {
  int t = blockIdx.x * blockDim.x + threadIdx.x;
  if (t >= 128 * 128) return;
  float w = W[t];
  unsigned short h = f2bf(w);
  whi[t] = h;
  wlo[t] = f2bf(w - bf2f(h));
}

// XW = X @ W.T via split-bf16 MFMA (Ahi*Bhi + Ahi*Blo + Alo*Bhi, f32 accum).
// Output written as bf16 (xwh) -- sole downstream representation.
__global__ __launch_bounds__(256, 2) void gemm_mfma_kernel(
    const float* __restrict__ X, const unsigned short* __restrict__ whi,
    const unsigned short* __restrict__ wlo, unsigned short* __restrict__ xwh, int n) {
  __shared__ unsigned short xh[128 * 136];   // +8 bf16 row pad
  __shared__ unsigned short xl[128 * 136];
  const int tid = threadIdx.x;
  const int row0 = blockIdx.x * 128;

#pragma unroll
  for (int i = 0; i < 16; ++i) {
    int f = tid + i * 256;                 // [0,4096) float4s
    int r = f >> 5, c4 = f & 31;
    int row = row0 + r;
    float4 v = make_float4(0.f, 0.f, 0.f, 0.f);
    if (row < n) v = reinterpret_cast<const float4*>(X)[(size_t)row * 32 + c4];
    ushort4 h, l;
    h.x = f2bf(v.x); l.x = f2bf(v.x - bf2f(h.x));
    h.y = f2bf(v.y); l.y = f2bf(v.y - bf2f(h.y));
    h.z = f2bf(v.z); l.z = f2bf(v.z - bf2f(h.z));
    h.w = f2bf(v.w); l.w = f2bf(v.w - bf2f(h.w));
    *reinterpret_cast<ushort4*>(&xh[r * 136 + c4 * 4]) = h;
    *reinterpret_cast<ushort4*>(&xl[r * 136 + c4 * 4]) = l;
  }
  __syncthreads();

  const int lane = tid & 63;
  const int wv = tid >> 6;
  const int wrow = wv * 32;
  const int lm = lane & 15;
  const int lk = lane >> 4;

#pragma unroll
  for (int nt = 0; nt < 8; ++nt) {
    const int n0 = nt * 16;
    bf16x8 bh[4], bl[4];
#pragma unroll
    for (int ks = 0; ks < 4; ++ks) {
      int baddr = (n0 + lm) * 128 + ks * 32 + lk * 8;
      bh[ks] = *reinterpret_cast<const bf16x8*>(&whi[baddr]);
      bl[ks] = *reinterpret_cast<const bf16x8*>(&wlo[baddr]);
    }
#pragma unroll
    for (int rt = 0; rt < 2; ++rt) {
      f32x4 acc = {0.f, 0.f, 0.f, 0.f};
#pragma unroll
      for (int ks = 0; ks < 4; ++ks) {
        int aoff = (wrow + rt * 16 + lm) * 136 + ks * 32 + lk * 8;
        bf16x8 ah = *reinterpret_cast<const bf16x8*>(&xh[aoff]);
        bf16x8 al = *reinterpret_cast<const bf16x8*>(&xl[aoff]);
        acc = __builtin_amdgcn_mfma_f32_16x16x32_bf16(ah, bh[ks], acc, 0, 0, 0);
        acc = __builtin_amdgcn_mfma_f32_16x16x32_bf16(ah, bl[ks], acc, 0, 0, 0);
        acc = __builtin_amdgcn_mfma_f32_16x16x32_bf16(al, bh[ks], acc, 0, 0, 0);
      }
      const int gcol = n0 + lm;
      const int grow = row0 + wrow + rt * 16 + lk * 4;
#pragma unroll
      for (int j = 0; j < 4; ++j) {
        if (grow + j < n) xwh[(size_t)(grow + j) * 128 + gcol] = f2bf(acc[j]);
      }
    }
  }
}

// a_src/a_dst per (node, head) from bf16 xw. 4 threads per node, 32 cols each.
__global__ void attn_node_kernel(const unsigned short* __restrict__ xwh,
                                 const float* __restrict__ att_s,
                                 const float* __restrict__ att_d,
                                 float* __restrict__ a_src, float* __restrict__ a_dst,
                                 int n) {
  int tid = blockIdx.x * blockDim.x + threadIdx.x;
  int node = tid >> 2;
  int q = tid & 3;
  if (node >= n) return;
  int h = q >> 1;
  const ushort8* xp = reinterpret_cast<const ushort8*>(xwh + (size_t)node * 128 + q * 32);
  float ss = 0.f, sd = 0.f;
#pragma unroll
  for (int u = 0; u < 4; ++u) {
    ushort8 v = xp[u];
    const float4* as4 = reinterpret_cast<const float4*>(att_s + q * 32 + u * 8);
    const float4* ad4 = reinterpret_cast<const float4*>(att_d + q * 32 + u * 8);
    float4 a0 = as4[0], a1 = as4[1];
    float4 d0 = ad4[0], d1 = ad4[1];
    float f0 = bf2f(v[0]), f1 = bf2f(v[1]), f2 = bf2f(v[2]), f3 = bf2f(v[3]);
    float f4 = bf2f(v[4]), f5 = bf2f(v[5]), f6 = bf2f(v[6]), f7 = bf2f(v[7]);
    ss += f0 * a0.x + f1 * a0.y + f2 * a0.z + f3 * a0.w
        + f4 * a1.x + f5 * a1.y + f6 * a1.z + f7 * a1.w;
    sd += f0 * d0.x + f1 * d0.y + f2 * d0.z + f3 * d0.w
        + f4 * d1.x + f5 * d1.y + f6 * d1.z + f7 * d1.w;
  }
  ss += __shfl_xor(ss, 1);
  sd += __shfl_xor(sd, 1);
  if ((q & 1) == 0) {
    a_src[node * 2 + h] = ss;
    a_dst[node * 2 + h] = sd;
  }
}

// --- CSR build (once; edges identical for both layers) ---
__global__ void hist_kernel(const void* __restrict__ edges, const int* __restrict__ isI32,
                            int E, int* __restrict__ deg) {
  int e = blockIdx.x * blockDim.x + threadIdx.x;
  if (e >= E) return;
  int i32 = *isI32;
  int s, d;
  load_edge(edges, i32, E, e, &s, &d);
  atomicAdd(&deg[d], 1);
}

__global__ void offsets_kernel(const int* __restrict__ deg, int* __restrict__ offs,
                               int* __restrict__ cursor, int* __restrict__ total, int n) {
  int t = blockIdx.x * blockDim.x + threadIdx.x;
  int lane = threadIdx.x & 63;
  int d = (t < n) ? deg[t] : 0;
  int pre = d;
#pragma unroll
  for (int sh = 1; sh < 64; sh <<= 1) {
    int v = __shfl_up(pre, sh);
    if (lane >= sh) pre += v;
  }
  int wavesum = __shfl(pre, 63);
  int base = 0;
  if (lane == 63) base = atomicAdd(total, wavesum);
  base = __shfl(base, 63);
  int start = base + pre - d;
  if (t < n) {
    offs[t] = start;
    cursor[t] = start;
  }
}

__global__ void scatter_kernel(const void* __restrict__ edges, const int* __restrict__ isI32,
                               int E, int* __restrict__ cursor, int* __restrict__ csr) {
  int e = blockIdx.x * blockDim.x + threadIdx.x;
  if (e >= E) return;
  int i32 = *isI32;
  int s, d;
  load_edge(edges, i32, E, e, &s, &d);
  int pos = atomicAdd(&cursor[d], 1);
  csr[pos] = s;
}

// --- Fused per-node GAT. One 64-lane wave per node.
// Phase C: four 16-lane quarters, each gathers one edge per step from bf16 xw
// (16 B/lane ushort8). All shuffles wave-uniform; tail predicated with cf=0.
__global__ __launch_bounds__(256) void gat_node_kernel(
    const unsigned short* __restrict__ xwh, const float* __restrict__ a_src,
    const float* __restrict__ a_dst, const int* __restrict__ offs,
    const int* __restrict__ degarr, const int* __restrict__ csr,
    const float* __restrict__ bias, float* __restrict__ out, int n) {
  const int node = (int)((blockIdx.x * (unsigned)blockDim.x + threadIdx.x) >> 6);
  const int lane = threadIdx.x & 63;
  if (node >= n) return;
  const int off = offs[node];
  const int deg = degarr[node];
  const float2 aself = reinterpret_cast<const float2*>(a_src)[node];
  const float2 ad = reinterpret_cast<const float2*>(a_dst)[node];

  // Phase A: max of a_src over in-neighbors (seed = self-loop).
  float m0 = aself.x, m1 = aself.y;
  int s_c = 0;
  float v0_c = NEG_BIG, v1_c = NEG_BIG;
  for (int base = 0; base < deg; base += 64) {
    int i = base + lane;
    int s = 0;
    float v0 = NEG_BIG, v1 = NEG_BIG;
    if (i < deg) {
      s = csr[off + i];
      float2 a = reinterpret_cast<const float2*>(a_src)[s];
      v0 = a.x; v1 = a.y;
    }
    if (base == 0) { s_c = s; v0_c = v0; v1_c = v1; }
    m0 = fmaxf(m0, v0);
    m1 = fmaxf(m1, v1);
  }
#pragma unroll
  for (int d = 32; d; d >>= 1) {
    m0 = fmaxf(m0, __shfl_xor(m0, d));
    m1 = fmaxf(m1, __shfl_xor(m1, d));
  }
  const float am0 = lrelu(ad.x + m0), am1 = lrelu(ad.y + m1);

  // Phase B: softmax denominator.
  float sum0 = 0.f, sum1 = 0.f;
  for (int base = 0; base < deg; base += 64) {
    int i = base + lane;
    float v0 = v0_c, v1 = v1_c;
    if (base != 0) {
      if (i < deg) {
        float2 a = reinterpret_cast<const float2*>(a_src)[csr[off + i]];
        v0 = a.x; v1 = a.y;
      } else { v0 = NEG_BIG; v1 = NEG_BIG; }
    }
    if (i < deg) {
      sum0 += expf(lrelu(v0 + ad.x) - am0);
      sum1 += expf(lrelu(v1 + ad.y) - am1);
    }
  }
#pragma unroll
  for (int d = 32; d; d >>= 1) {
    sum0 += __shfl_xor(sum0, d);
    sum1 += __shfl_xor(sum1, d);
  }
  const float es0 = expf(lrelu(aself.x + ad.x) - am0);
  const float es1 = expf(lrelu(aself.y + ad.y) - am1);
  sum0 += es0; sum1 += es1;
  const float r0 = 1.f / (sum0 + SM_EPS);
  const float r1 = 1.f / (sum1 + SM_EPS);

  // Phase C: quarter-wave gather. Lane -> quarter qt, slot ql (8 cols), head hq.
  const int qt = lane >> 4;
  const int ql = lane & 15;
  const int hq = ql >> 3;
  float a8[8] = {0.f, 0.f, 0.f, 0.f, 0.f, 0.f, 0.f, 0.f};
  if (qt == 0) {
    const float selfc = (hq == 0) ? es0 * r0 : es1 * r1;
    ushort8 xs8 = *reinterpret_cast<const ushort8*>(&xwh[(size_t)node * 128 + ql * 8]);
    const float4* bv = reinterpret_cast<const float4*>(bias);
    float4 b0 = bv[ql * 2], b1 = bv[ql * 2 + 1];
    a8[0] = b0.x + selfc * bf2f(xs8[0]);
    a8[1] = b0.y + selfc * bf2f(xs8[1]);
    a8[2] = b0.z + selfc * bf2f(xs8[2]);
    a8[3] = b0.w + selfc * bf2f(xs8[3]);
    a8[4] = b1.x + selfc * bf2f(xs8[4]);
    a8[5] = b1.y + selfc * bf2f(xs8[5]);
    a8[6] = b1.z + selfc * bf2f(xs8[6]);
    a8[7] = b1.w + selfc * bf2f(xs8[7]);
  }

  for (int base = 0; base < deg; base += 64) {
    int i = base + lane;
    int s = s_c;
    float c0, c1;
    if (base == 0) {
      c0 = expf(lrelu(v0_c + ad.x) - am0) * r0;
      c1 = expf(lrelu(v1_c + ad.y) - am1) * r1;
    } else if (i < deg) {
      s = csr[off + i];
      float2 a = reinterpret_cast<const float2*>(a_src)[s];
      c0 = expf(lrelu(a.x + ad.x) - am0) * r0;
      c1 = expf(lrelu(a.y + ad.y) - am1) * r1;
    } else { s = 0; c0 = 0.f; c1 = 0.f; }
    const int cnt = min(64, deg - base);
    for (int jb = 0; jb < cnt; jb += 4) {
      int j = jb + qt;
      int jc = j < cnt ? j : 0;
      int sj = __shfl(s, jc);
      float cf0 = __shfl(c0, jc);
      float cf1 = __shfl(c1, jc);
      float cf = hq ? cf1 : cf0;
      if (j >= cnt) cf = 0.f;
      ushort8 v = *reinterpret_cast<const ushort8*>(&xwh[(size_t)sj * 128 + ql * 8]);
#pragma unroll
      for (int k = 0; k < 8; ++k) a8[k] += cf * bf2f(v[k]);
    }
  }

  // reduce across quarters
#pragma unroll
  for (int k = 0; k < 8; ++k) {
    a8[k] += __shfl_xor(a8[k], 16);
    a8[k] += __shfl_xor(a8[k], 32);
  }

  if (qt == 0) {
#pragma unroll
    for (int k = 0; k < 8; ++k) a8[k] = a8[k] > 0.f ? a8[k] : expm1f(a8[k]);
    float4* op = reinterpret_cast<float4*>(out + (size_t)node * 128 + ql * 8);
    op[0] = make_float4(a8[0], a8[1], a8[2], a8[3]);
    op[1] = make_float4(a8[4], a8[5], a8[6], a8[7]);
  }
}

extern "C" void kernel_launch(void* const* d_in, const int* in_sizes, int n_in,
                              void* d_out, int out_size, void* d_ws, size_t ws_size,
                              hipStream_t stream) {
  const float* x    = (const float*)d_in[0];
  const void* edges = d_in[1];
  const float* W0  = (const float*)d_in[2];
  const float* as0 = (const float*)d_in[3];
  const float* ad0 = (const float*)d_in[4];
  const float* b0  = (const float*)d_in[5];
  const float* W1  = (const float*)d_in[6];
  const float* as1 = (const float*)d_in[7];
  const float* ad1 = (const float*)d_in[8];
  const float* b1  = (const float*)d_in[9];
  float* out = (float*)d_out;

  const int n = in_sizes[0] / 128;
  const int E = in_sizes[1] / 2;

  unsigned short* xwh = (unsigned short*)d_ws;            // n*128 bf16
  float* hbuf  = (float*)(xwh + (size_t)n * 128);         // n*128 f32
  float* a_src = hbuf + (size_t)n * 128;
  float* a_dst = a_src + 2 * (size_t)n;
  int* offs    = (int*)(a_dst + 2 * (size_t)n);  // n
  int* deg     = offs + n;                       // n
  int* cursor  = deg + n;                        // n
  int* csr     = cursor + n;                     // E
  int* flag    = csr + E;                        // 1
  int* total   = flag + 1;                       // 1
  unsigned short* whi = (unsigned short*)(total + 1);  // 16384
  unsigned short* wlo = whi + 128 * 128;               // 16384

  hipMemsetAsync(flag, 0, 2 * sizeof(int), stream);
  hipMemsetAsync(deg, 0, (size_t)n * sizeof(int), stream);

  int dcount = E < 4096 ? E : 4096;
  detect_i32_kernel<<<(dcount + 255) / 256, 256, 0, stream>>>(
      (const unsigned long long*)edges, dcount, (unsigned long long)n, flag);

  hist_kernel<<<(E + 255) / 256, 256, 0, stream>>>(edges, flag, E, deg);
  offsets_kernel<<<(n + 255) / 256, 256, 0, stream>>>(deg, offs, cursor, total, n);
  scatter_kernel<<<(E + 255) / 256, 256, 0, stream>>>(edges, flag, E, cursor, csr);

  const float* in_feat = x;
  for (int layer = 0; layer < 2; ++layer) {
    const float* W   = layer ? W1 : W0;
    const float* as_ = layer ? as1 : as0;
    const float* ad_ = layer ? ad1 : ad0;
    const float* bs  = layer ? b1 : b0;
    float* acc = layer ? out : hbuf;

    wconv_kernel<<<64, 256, 0, stream>>>(W, whi, wlo);
    gemm_mfma_kernel<<<(n + 127) / 128, 256, 0, stream>>>(in_feat, whi, wlo, xwh, n);
    attn_node_kernel<<<(n * 4 + 255) / 256, 256, 0, stream>>>(xwh, as_, ad_, a_src, a_dst, n);
    gat_node_kernel<<<(n + 3) / 4, 256, 0, stream>>>(xwh, a_src, a_dst, offs, deg, csr, bs, acc, n);

    in_feat = hbuf;
  }
}

// Round 8
// 260.059 us; speedup vs baseline: 12.4631x; 1.0886x over previous
//
#include <hip/hip_runtime.h>

constexpr float NEG_SLOPE = 0.2f;
constexpr float SM_EPS = 1e-16f;
#define NEG_BIG (-3.0e38f)

typedef __bf16 bf16x8 __attribute__((ext_vector_type(8)));
typedef float f32x4 __attribute__((ext_vector_type(4)));
typedef unsigned short ushort8 __attribute__((ext_vector_type(8)));

__device__ __forceinline__ float lrelu(float x) { return x > 0.f ? x : NEG_SLOPE * x; }

// f32 -> bf16 round-nearest-even (finite inputs)
__device__ __forceinline__ unsigned short f2bf(float f) {
  unsigned u = __float_as_uint(f);
  unsigned r = u + 0x7FFFu + ((u >> 16) & 1u);
  return (unsigned short)(r >> 16);
}
__device__ __forceinline__ float bf2f(unsigned short h) {
  return __uint_as_float((unsigned)h << 16);
}

__device__ __forceinline__ void load_edge(const void* edges, int i32, int E, int e,
                                          int* s, int* d) {
  if (i32) {
    *s = ((const int*)edges)[e];
    *d = ((const int*)edges)[E + e];
  } else {
    *s = (int)((const long long*)edges)[e];
    *d = (int)((const long long*)edges)[E + e];
  }
}

__global__ void detect_i32_kernel(const unsigned long long* __restrict__ e, int count,
                                  unsigned long long n, int* flag) {
  int t = blockIdx.x * blockDim.x + threadIdx.x;
  if (t < count && e[t] >= n) atomicOr(flag, 1);
}

// Split W (128x128 f32) into bf16 hi/lo once per layer.
__global__ void wconv_kernel(const float* __restrict__ W, unsigned short* __restrict__ whi,
                             unsigned short* __restrict__ wlo) {
  int t = blockIdx.x * blockDim.x + threadIdx.x;
  if (t >= 128 * 128) return;
  float w = W[t];
  unsigned short h = f2bf(w);
  whi[t] = h;
  wlo[t] = f2bf(w - bf2f(h));
}

// XW = X @ W.T via split-bf16 MFMA (Ahi*Bhi + Ahi*Blo + Alo*Bhi, f32 accum).
// Output bf16 (xwh). Fused epilogue: a_src/a_dst attention dots accumulated
// from the f32 acc tiles and flushed at head boundaries (nt==3, nt==7).
__global__ __launch_bounds__(256, 2) void gemm_mfma_kernel(
    const float* __restrict__ X, const unsigned short* __restrict__ whi,
    const unsigned short* __restrict__ wlo, const float* __restrict__ att_s,
    const float* __restrict__ att_d, unsigned short* __restrict__ xwh,
    float* __restrict__ a_src, float* __restrict__ a_dst, int n) {
  __shared__ unsigned short xh[128 * 136];   // +8 bf16 row pad
  __shared__ unsigned short xl[128 * 136];
  const int tid = threadIdx.x;
  const int row0 = blockIdx.x * 128;

#pragma unroll
  for (int i = 0; i < 16; ++i) {
    int f = tid + i * 256;                 // [0,4096) float4s
    int r = f >> 5, c4 = f & 31;
    int row = row0 + r;
    float4 v = make_float4(0.f, 0.f, 0.f, 0.f);
    if (row < n) v = reinterpret_cast<const float4*>(X)[(size_t)row * 32 + c4];
    ushort4 h, l;
    h.x = f2bf(v.x); l.x = f2bf(v.x - bf2f(h.x));
    h.y = f2bf(v.y); l.y = f2bf(v.y - bf2f(h.y));
    h.z = f2bf(v.z); l.z = f2bf(v.z - bf2f(h.z));
    h.w = f2bf(v.w); l.w = f2bf(v.w - bf2f(h.w));
    *reinterpret_cast<ushort4*>(&xh[r * 136 + c4 * 4]) = h;
    *reinterpret_cast<ushort4*>(&xl[r * 136 + c4 * 4]) = l;
  }
  __syncthreads();

  const int lane = tid & 63;
  const int wv = tid >> 6;
  const int wrow = wv * 32;
  const int lm = lane & 15;
  const int lk = lane >> 4;

  float asp[2][4] = {{0.f, 0.f, 0.f, 0.f}, {0.f, 0.f, 0.f, 0.f}};
  float adp[2][4] = {{0.f, 0.f, 0.f, 0.f}, {0.f, 0.f, 0.f, 0.f}};

#pragma unroll
  for (int nt = 0; nt < 8; ++nt) {
    const int n0 = nt * 16;
    bf16x8 bh[4], bl[4];
#pragma unroll
    for (int ks = 0; ks < 4; ++ks) {
      int baddr = (n0 + lm) * 128 + ks * 32 + lk * 8;
      bh[ks] = *reinterpret_cast<const bf16x8*>(&whi[baddr]);
      bl[ks] = *reinterpret_cast<const bf16x8*>(&wlo[baddr]);
    }
    const float sa = att_s[n0 + lm];
    const float da = att_d[n0 + lm];
#pragma unroll
    for (int rt = 0; rt < 2; ++rt) {
      f32x4 acc = {0.f, 0.f, 0.f, 0.f};
#pragma unroll
      for (int ks = 0; ks < 4; ++ks) {
        int aoff = (wrow + rt * 16 + lm) * 136 + ks * 32 + lk * 8;
        bf16x8 ah = *reinterpret_cast<const bf16x8*>(&xh[aoff]);
        bf16x8 al = *reinterpret_cast<const bf16x8*>(&xl[aoff]);
        acc = __builtin_amdgcn_mfma_f32_16x16x32_bf16(ah, bh[ks], acc, 0, 0, 0);
        acc = __builtin_amdgcn_mfma_f32_16x16x32_bf16(ah, bl[ks], acc, 0, 0, 0);
        acc = __builtin_amdgcn_mfma_f32_16x16x32_bf16(al, bh[ks], acc, 0, 0, 0);
      }
      const int gcol = n0 + lm;
      const int grow = row0 + wrow + rt * 16 + lk * 4;
#pragma unroll
      for (int j = 0; j < 4; ++j) {
        asp[rt][j] += acc[j] * sa;
        adp[rt][j] += acc[j] * da;
        if (grow + j < n) xwh[(size_t)(grow + j) * 128 + gcol] = f2bf(acc[j]);
      }
    }
    if (nt == 3 || nt == 7) {
      const int h = nt >> 2;
#pragma unroll
      for (int rt = 0; rt < 2; ++rt)
#pragma unroll
        for (int j = 0; j < 4; ++j) {
          float v1 = asp[rt][j], v2 = adp[rt][j];
#pragma unroll
          for (int dsh = 1; dsh < 16; dsh <<= 1) {
            v1 += __shfl_xor(v1, dsh);
            v2 += __shfl_xor(v2, dsh);
          }
          if (lm == 0) {
            int row = row0 + wrow + rt * 16 + lk * 4 + j;
            if (row < n) {
              a_src[row * 2 + h] = v1;
              a_dst[row * 2 + h] = v2;
            }
          }
          asp[rt][j] = 0.f;
          adp[rt][j] = 0.f;
        }
    }
  }
}

// --- CSR build (once; edges identical for both layers) ---
__global__ void hist_kernel(const void* __restrict__ edges, const int* __restrict__ isI32,
                            int E, int* __restrict__ deg) {
  int e = blockIdx.x * blockDim.x + threadIdx.x;
  if (e >= E) return;
  int d;
  if (*isI32) d = ((const int*)edges)[E + e];
  else        d = (int)((const long long*)edges)[E + e];
  atomicAdd(&deg[d], 1);
}

// Parallel segment allocator: per-wave prefix sum + 1 atomic per wave.
__global__ void offsets_kernel(const int* __restrict__ deg, int* __restrict__ offs,
                               int* __restrict__ cursor, int* __restrict__ total, int n) {
  int t = blockIdx.x * blockDim.x + threadIdx.x;
  int lane = threadIdx.x & 63;
  int d = (t < n) ? deg[t] : 0;
  int pre = d;
#pragma unroll
  for (int sh = 1; sh < 64; sh <<= 1) {
    int v = __shfl_up(pre, sh);
    if (lane >= sh) pre += v;
  }
  int wavesum = __shfl(pre, 63);
  int base = 0;
  if (lane == 63) base = atomicAdd(total, wavesum);
  base = __shfl(base, 63);
  int start = base + pre - d;
  if (t < n) {
    offs[t] = start;
    cursor[t] = start;
  }
}

template <typename IT>
__global__ void scatter_kernel(const void* __restrict__ edges, const int* __restrict__ isI32,
                               int E, int* __restrict__ cursor, IT* __restrict__ csr) {
  int e = blockIdx.x * blockDim.x + threadIdx.x;
  if (e >= E) return;
  int i32 = *isI32;
  int s, d;
  load_edge(edges, i32, E, e, &s, &d);
  int pos = atomicAdd(&cursor[d], 1);
  csr[pos] = (IT)s;
}

// --- Fused per-node GAT. One 64-lane wave per node.
// Phase C: four 16-lane quarters, each gathers one edge per step from bf16 xw
// (16 B/lane ushort8). All shuffles wave-uniform; tail predicated with cf=0.
template <typename IT>
__global__ __launch_bounds__(256) void gat_node_kernel(
    const unsigned short* __restrict__ xwh, const float* __restrict__ a_src,
    const float* __restrict__ a_dst, const int* __restrict__ offs,
    const int* __restrict__ degarr, const IT* __restrict__ csr,
    const float* __restrict__ bias, float* __restrict__ out, int n) {
  const int node = (int)((blockIdx.x * (unsigned)blockDim.x + threadIdx.x) >> 6);
  const int lane = threadIdx.x & 63;
  if (node >= n) return;
  const int off = offs[node];
  const int deg = degarr[node];
  const float2 aself = reinterpret_cast<const float2*>(a_src)[node];
  const float2 ad = reinterpret_cast<const float2*>(a_dst)[node];

  // Phase A: max of a_src over in-neighbors (seed = self-loop).
  float m0 = aself.x, m1 = aself.y;
  int s_c = 0;
  float v0_c = NEG_BIG, v1_c = NEG_BIG;
  for (int base = 0; base < deg; base += 64) {
    int i = base + lane;
    int s = 0;
    float v0 = NEG_BIG, v1 = NEG_BIG;
    if (i < deg) {
      s = (int)csr[off + i];
      float2 a = reinterpret_cast<const float2*>(a_src)[s];
      v0 = a.x; v1 = a.y;
    }
    if (base == 0) { s_c = s; v0_c = v0; v1_c = v1; }
    m0 = fmaxf(m0, v0);
    m1 = fmaxf(m1, v1);
  }
#pragma unroll
  for (int d = 32; d; d >>= 1) {
    m0 = fmaxf(m0, __shfl_xor(m0, d));
    m1 = fmaxf(m1, __shfl_xor(m1, d));
  }
  const float am0 = lrelu(ad.x + m0), am1 = lrelu(ad.y + m1);

  // Phase B: softmax denominator.
  float sum0 = 0.f, sum1 = 0.f;
  for (int base = 0; base < deg; base += 64) {
    int i = base + lane;
    float v0 = v0_c, v1 = v1_c;
    if (base != 0) {
      if (i < deg) {
        float2 a = reinterpret_cast<const float2*>(a_src)[(int)csr[off + i]];
        v0 = a.x; v1 = a.y;
      } else { v0 = NEG_BIG; v1 = NEG_BIG; }
    }
    if (i < deg) {
      sum0 += expf(lrelu(v0 + ad.x) - am0);
      sum1 += expf(lrelu(v1 + ad.y) - am1);
    }
  }
#pragma unroll
  for (int d = 32; d; d >>= 1) {
    sum0 += __shfl_xor(sum0, d);
    sum1 += __shfl_xor(sum1, d);
  }
  const float es0 = expf(lrelu(aself.x + ad.x) - am0);
  const float es1 = expf(lrelu(aself.y + ad.y) - am1);
  sum0 += es0; sum1 += es1;
  const float r0 = 1.f / (sum0 + SM_EPS);
  const float r1 = 1.f / (sum1 + SM_EPS);

  // Phase C: quarter-wave gather. Lane -> quarter qt, slot ql (8 cols), head hq.
  const int qt = lane >> 4;
  const int ql = lane & 15;
  const int hq = ql >> 3;
  float a8[8] = {0.f, 0.f, 0.f, 0.f, 0.f, 0.f, 0.f, 0.f};
  if (qt == 0) {
    const float selfc = (hq == 0) ? es0 * r0 : es1 * r1;
    ushort8 xs8 = *reinterpret_cast<const ushort8*>(&xwh[(size_t)node * 128 + ql * 8]);
    const float4* bv = reinterpret_cast<const float4*>(bias);
    float4 b0 = bv[ql * 2], b1 = bv[ql * 2 + 1];
    a8[0] = b0.x + selfc * bf2f(xs8[0]);
    a8[1] = b0.y + selfc * bf2f(xs8[1]);
    a8[2] = b0.z + selfc * bf2f(xs8[2]);
    a8[3] = b0.w + selfc * bf2f(xs8[3]);
    a8[4] = b1.x + selfc * bf2f(xs8[4]);
    a8[5] = b1.y + selfc * bf2f(xs8[5]);
    a8[6] = b1.z + selfc * bf2f(xs8[6]);
    a8[7] = b1.w + selfc * bf2f(xs8[7]);
  }

  for (int base = 0; base < deg; base += 64) {
    int i = base + lane;
    int s = s_c;
    float c0, c1;
    if (base == 0) {
      c0 = expf(lrelu(v0_c + ad.x) - am0) * r0;
      c1 = expf(lrelu(v1_c + ad.y) - am1) * r1;
    } else if (i < deg) {
      s = (int)csr[off + i];
      float2 a = reinterpret_cast<const float2*>(a_src)[s];
      c0 = expf(lrelu(a.x + ad.x) - am0) * r0;
      c1 = expf(lrelu(a.y + ad.y) - am1) * r1;
    } else { s = 0; c0 = 0.f; c1 = 0.f; }
    const int cnt = min(64, deg - base);
    for (int jb = 0; jb < cnt; jb += 4) {
      int j = jb + qt;
      int jc = j < cnt ? j : 0;
      int sj = __shfl(s, jc);
      float cf0 = __shfl(c0, jc);
      float cf1 = __shfl(c1, jc);
      float cf = hq ? cf1 : cf0;
      if (j >= cnt) cf = 0.f;
      ushort8 v = *reinterpret_cast<const ushort8*>(&xwh[(size_t)sj * 128 + ql * 8]);
#pragma unroll
      for (int k = 0; k < 8; ++k) a8[k] += cf * bf2f(v[k]);
    }
  }

#pragma unroll
  for (int k = 0; k < 8; ++k) {
    a8[k] += __shfl_xor(a8[k], 16);
    a8[k] += __shfl_xor(a8[k], 32);
  }

  if (qt == 0) {
#pragma unroll
    for (int k = 0; k < 8; ++k) a8[k] = a8[k] > 0.f ? a8[k] : expm1f(a8[k]);
    float4* op = reinterpret_cast<float4*>(out + (size_t)node * 128 + ql * 8);
    op[0] = make_float4(a8[0], a8[1], a8[2], a8[3]);
    op[1] = make_float4(a8[4], a8[5], a8[6], a8[7]);
  }
}

extern "C" void kernel_launch(void* const* d_in, const int* in_sizes, int n_in,
                              void* d_out, int out_size, void* d_ws, size_t ws_size,
                              hipStream_t stream) {
  const float* x    = (const float*)d_in[0];
  const void* edges = d_in[1];
  const float* W0  = (const float*)d_in[2];
  const float* as0 = (const float*)d_in[3];
  const float* ad0 = (const float*)d_in[4];
  const float* b0  = (const float*)d_in[5];
  const float* W1  = (const float*)d_in[6];
  const float* as1 = (const float*)d_in[7];
  const float* ad1 = (const float*)d_in[8];
  const float* b1  = (const float*)d_in[9];
  float* out = (float*)d_out;

  const int n = in_sizes[0] / 128;
  const int E = in_sizes[1] / 2;
  const bool use16 = (n <= 65535);

  unsigned short* xwh = (unsigned short*)d_ws;            // n*128 bf16
  float* hbuf  = (float*)(xwh + (size_t)n * 128);         // n*128 f32
  float* a_src = hbuf + (size_t)n * 128;
  float* a_dst = a_src + 2 * (size_t)n;
  int* offs    = (int*)(a_dst + 2 * (size_t)n);  // n
  int* deg     = offs + n;                       // n
  int* cursor  = deg + n;                        // n
  int* csr     = cursor + n;                     // E ints (or E ushorts within)
  int* flag    = csr + E;                        // 1
  int* total   = flag + 1;                       // 1
  unsigned short* whi = (unsigned short*)(total + 1);  // 16384
  unsigned short* wlo = whi + 128 * 128;               // 16384

  hipMemsetAsync(flag, 0, 2 * sizeof(int), stream);
  hipMemsetAsync(deg, 0, (size_t)n * sizeof(int), stream);

  int dcount = E < 4096 ? E : 4096;
  detect_i32_kernel<<<(dcount + 255) / 256, 256, 0, stream>>>(
      (const unsigned long long*)edges, dcount, (unsigned long long)n, flag);

  hist_kernel<<<(E + 255) / 256, 256, 0, stream>>>(edges, flag, E, deg);
  offsets_kernel<<<(n + 255) / 256, 256, 0, stream>>>(deg, offs, cursor, total, n);
  if (use16)
    scatter_kernel<unsigned short><<<(E + 255) / 256, 256, 0, stream>>>(
        edges, flag, E, cursor, (unsigned short*)csr);
  else
    scatter_kernel<int><<<(E + 255) / 256, 256, 0, stream>>>(edges, flag, E, cursor, csr);

  const float* in_feat = x;
  for (int layer = 0; layer < 2; ++layer) {
    const float* W   = layer ? W1 : W0;
    const float* as_ = layer ? as1 : as0;
    const float* ad_ = layer ? ad1 : ad0;
    const float* bs  = layer ? b1 : b0;
    float* acc = layer ? out : hbuf;

    wconv_kernel<<<64, 256, 0, stream>>>(W, whi, wlo);
    gemm_mfma_kernel<<<(n + 127) / 128, 256, 0, stream>>>(
        in_feat, whi, wlo, as_, ad_, xwh, a_src, a_dst, n);
    if (use16)
      gat_node_kernel<unsigned short><<<(n + 3) / 4, 256, 0, stream>>>(
          xwh, a_src, a_dst, offs, deg, (const unsigned short*)csr, bs, acc, n);
    else
      gat_node_kernel<int><<<(n + 3) / 4, 256, 0, stream>>>(
          xwh, a_src, a_dst, offs, deg, csr, bs, acc, n);

    in_feat = hbuf;
  }
}